// Round 1
// baseline (718.109 us; speedup 1.0000x reference)
//
#include <hip/hip_runtime.h>

#define ALPHA 0.5f
#define BSHIFT 11                // 2048 rows per bucket
#define RPB 2048
#define MAXB 256                 // >= nBuckets (147)
#define CHUNK 8192               // edges per partition block

// ---------------- bf16 / vector helpers ----------------

typedef float f4 __attribute__((ext_vector_type(4)));
typedef unsigned int u2 __attribute__((ext_vector_type(2)));

__device__ __forceinline__ float bf2f(unsigned short u) {
  return __uint_as_float((unsigned)u << 16);
}
__device__ __forceinline__ unsigned short f2bf(float f) {
  unsigned u = __float_as_uint(f);
  u += 0x7fffu + ((u >> 16) & 1u);   // round-to-nearest-even
  return (unsigned short)(u >> 16);
}

// non-temporal streaming accessors (keep L2 for the random gathers)
__device__ __forceinline__ f4 ldnt_f4(const float* p) {
  return __builtin_nontemporal_load((const f4*)p);
}
__device__ __forceinline__ unsigned long long ldnt_u64(const int2* p) {
  return __builtin_nontemporal_load((const unsigned long long*)p);
}
__device__ __forceinline__ void stnt_u2(unsigned short* p, unsigned lo, unsigned hi) {
  u2 v; v.x = lo; v.y = hi;
  __builtin_nontemporal_store(v, (u2*)p);
}

// ---------------- fused: bucket counts (blocks 0..511) + f32->bf16 convert ----------------

__global__ __launch_bounds__(256) void k_conv_bucket(
    const int* __restrict__ rows, int nnz, int* __restrict__ bcnt,
    const float* __restrict__ uE, const float* __restrict__ iE,
    int nU64, int nTot, unsigned short* __restrict__ out) {
  __shared__ int lcnt[MAXB];
  int t = threadIdx.x;
  if (blockIdx.x < 512) {
    if (t < MAXB) lcnt[t] = 0;
    __syncthreads();
    int stride = 512 * 256;
    for (int e = blockIdx.x * 256 + t; e < nnz; e += stride)
      atomicAdd(&lcnt[rows[e] >> BSHIFT], 1);
    __syncthreads();
    if (t < MAXB) {
      int c = lcnt[t];
      if (c) atomicAdd(&bcnt[t], c);
    }
  } else {
    int i = ((int)(blockIdx.x - 512) * 256 + t) * 4;
    if (i >= nTot) return;
    const float* src = (i < nU64) ? (uE + i) : (iE + (i - nU64));
    f4 v = ldnt_f4(src);
    unsigned lo = (unsigned)f2bf(v.x) | ((unsigned)f2bf(v.y) << 16);
    unsigned hi = (unsigned)f2bf(v.z) | ((unsigned)f2bf(v.w) << 16);
    stnt_u2(out + i, lo, hi);
  }
}

// ---------------- scan bucket counts -> bptr, bcur ----------------

__global__ void k_scan_buckets(const int* __restrict__ bcnt, int nb,
                               int* __restrict__ bptr, int* __restrict__ bcur) {
  __shared__ int s[256];
  int t = threadIdx.x;
  int v = (t < nb) ? bcnt[t] : 0;
  s[t] = v; __syncthreads();
  for (int d = 1; d < 256; d <<= 1) {
    int x = (t >= d) ? s[t - d] : 0;
    __syncthreads();
    s[t] += x;
    __syncthreads();
  }
  if (t < nb) {
    int excl = s[t] - v;
    bptr[t] = excl;
    bcur[t] = excl;
  }
  if (t == 0) bptr[nb] = s[255];   // total
}

// ---------------- partition edges into buckets (packed 8B payload) ----------------

__global__ __launch_bounds__(256) void k_partition(
    const int* __restrict__ rows, const int* __restrict__ cols, const float* __restrict__ vals,
    int nnz, int* __restrict__ bcur, uint2* __restrict__ pPay) {
  __shared__ int lcnt[MAXB];
  __shared__ int lbase[MAXB];
  int t = threadIdx.x;
  if (t < MAXB) lcnt[t] = 0;
  __syncthreads();
  int base = blockIdx.x * CHUNK;
  int end = nnz < base + CHUNK ? nnz : base + CHUNK;
  for (int e = base + t; e < end; e += 256)
    atomicAdd(&lcnt[rows[e] >> BSHIFT], 1);
  __syncthreads();
  if (t < MAXB) {
    int c = lcnt[t];
    lbase[t] = c ? atomicAdd(&bcur[t], c) : 0;
    lcnt[t] = 0;
  }
  __syncthreads();
  for (int e = base + t; e < end; e += 256) {
    int r = rows[e];
    int b = r >> BSHIFT;
    int p = lbase[b] + atomicAdd(&lcnt[b], 1);
    uint2 pay;
    pay.x = ((unsigned)(r & (RPB - 1)) << 20) | (unsigned)cols[e];
    pay.y = __float_as_uint(vals[e]);
    pPay[p] = pay;
  }
}

// ---------------- per-bucket CSR build + degree histogram ----------------

__global__ __launch_bounds__(256) void k_build_csr(
    const int* __restrict__ bptr, const uint2* __restrict__ pPay, int N,
    int* __restrict__ rowptr, int* __restrict__ cnt, int2* __restrict__ colval,
    int* __restrict__ degHist) {
  __shared__ int lcnt[RPB];        // 8 KB: counts -> cursors
  __shared__ int scanbuf[256];
  __shared__ int ldeg[256];
  int t = threadIdx.x;
  int b = blockIdx.x;
  int r0 = b << BSHIFT;
  int rCount = N - r0; if (rCount > RPB) rCount = RPB;
  int eBeg = bptr[b], eEnd = bptr[b + 1];

  for (int r = t; r < RPB; r += 256) lcnt[r] = 0;
  ldeg[t] = 0;
  __syncthreads();
  for (int e = eBeg + t; e < eEnd; e += 256)
    atomicAdd(&lcnt[pPay[e].x >> 20], 1);
  __syncthreads();
  for (int r = t; r < rCount; r += 256) {
    int c = lcnt[r];
    cnt[r0 + r] = c;
    atomicAdd(&ldeg[c < 255 ? c : 255], 1);
  }
  int v8[8]; int s = 0;
#pragma unroll
  for (int k = 0; k < 8; k++) {
    int x = lcnt[8 * t + k];
    v8[k] = s; s += x;
  }
  scanbuf[t] = s; __syncthreads();
  for (int d = 1; d < 256; d <<= 1) {
    int x = (t >= d) ? scanbuf[t - d] : 0;
    __syncthreads();
    scanbuf[t] += x;
    __syncthreads();
  }
  int blockExcl = scanbuf[t] - s;
#pragma unroll
  for (int k = 0; k < 8; k++) lcnt[8 * t + k] = blockExcl + v8[k];
  __syncthreads();
  if (ldeg[t]) atomicAdd(&degHist[t], ldeg[t]);
  for (int r = t; r < rCount; r += 256) rowptr[r0 + r] = eBeg + lcnt[r];
  __syncthreads();
  for (int e = eBeg + t; e < eEnd; e += 256) {
    uint2 pay = pPay[e];
    int r = (int)(pay.x >> 20);
    int p = eBeg + atomicAdd(&lcnt[r], 1);
    int2 cv; cv.x = (int)(pay.x & 0xFFFFFu); cv.y = (int)pay.y;
    colval[p] = cv;
  }
}

// ---------------- degree-bin scan (1 block) + colval pad init ----------------

__global__ void k_degscan(const int* __restrict__ degHist, int* __restrict__ degCur,
                          int2* __restrict__ colval, int nnz) {
  __shared__ int s[256];
  int t = threadIdx.x;
  int v = degHist[t];
  s[t] = v; __syncthreads();
  for (int d = 1; d < 256; d <<= 1) {
    int x = (t >= d) ? s[t - d] : 0;
    __syncthreads();
    s[t] += x;
    __syncthreads();
  }
  degCur[t] = s[t] - v;   // exclusive
  if (t < 8) { int2 z; z.x = 0; z.y = 0; colval[nnz + t] = z; }
}

// ---------------- permute rows into degree-sorted order ----------------

__global__ __launch_bounds__(256) void k_permute(
    const int* __restrict__ rowptr, const int* __restrict__ cnt, int N,
    int* __restrict__ degCur,
    int* __restrict__ perm, int* __restrict__ rowptrS, int* __restrict__ lenS) {
  __shared__ int lcnt[256];
  __shared__ int lbase[256];
  int t = threadIdx.x;
  lcnt[t] = 0;
  __syncthreads();
  int base = blockIdx.x * 1024;
  int end = N < base + 1024 ? N : base + 1024;
  for (int r = base + t; r < end; r += 256) {
    int c = cnt[r];
    atomicAdd(&lcnt[c < 255 ? c : 255], 1);
  }
  __syncthreads();
  {
    int c = lcnt[t];
    lbase[t] = c ? atomicAdd(&degCur[t], c) : 0;
    lcnt[t] = 0;
  }
  __syncthreads();
  for (int r = base + t; r < end; r += 256) {
    int c = cnt[r];
    int bin = c < 255 ? c : 255;
    int pos = lbase[bin] + atomicAdd(&lcnt[bin], 1);
    perm[pos] = r;
    rowptrS[pos] = rowptr[r];
    lenS[pos] = c;
  }
}

// ---------------- SpMM core: quarter-wave owns 2 degree-adjacent rows ----------------
// Software-pipelined: colval group for iteration j+4 is prefetched while the
// gathers for iteration j are in flight (breaks the cv->gather serial chain).
// 4-edge unroll per row => 8 gathers in flight per lane.

__device__ __forceinline__ void spmm_body(
    int gtid,
    const unsigned short* __restrict__ src,
    const float* __restrict__ e0U, const float* __restrict__ e0I, int split,
    const int* __restrict__ perm, const int* __restrict__ rowptrS, const int* __restrict__ lenS,
    const int2* __restrict__ colval,
    unsigned short* __restrict__ dst, int n) {
  int wave = gtid >> 6;
  int lane = gtid & 63;
  int sub = lane >> 4;
  int k   = lane & 15;
  int q = wave * 4 + sub;
  int s0 = 2 * q, s1 = 2 * q + 1;
  bool va = s0 < n, vb = s1 < n;
  int i0 = va ? s0 : 0, i1 = vb ? s1 : 0;
  int row0 = perm[i0], row1 = perm[i1];
  int st0 = rowptrS[i0], st1 = rowptrS[i1];
  int len0 = va ? lenS[i0] : 0, len1 = vb ? lenS[i1] : 0;
  const int2* cv0 = colval + st0;
  const int2* cv1 = colval + st1;
  const unsigned short* srcK = src + (size_t)k * 4;
  int l0m = len0 > 0 ? len0 - 1 : 0;
  int l1m = len1 > 0 ? len1 - 1 : 0;
  int mx = max(len0, len1);

  float p0 = 0.f, p1 = 0.f, p2 = 0.f, p3 = 0.f;     // row0 acc
  float r0 = 0.f, r1 = 0.f, r2 = 0.f, r3 = 0.f;     // row1 acc

  // preload colval group for j = 0..3 (packed col | weight in 8B)
  unsigned long long cA[4], cB[4];
#pragma unroll
  for (int u = 0; u < 4; u++) {
    int jA = u < l0m ? u : l0m;
    int jB = u < l1m ? u : l1m;
    cA[u] = ldnt_u64(cv0 + jA);
    cB[u] = ldnt_u64(cv1 + jB);
  }

  for (int j = 0; j < mx; j += 4) {
    // extract weights for the current group before the registers are reloaded
    float wA[4], wB[4];
#pragma unroll
    for (int u = 0; u < 4; u++) {
      wA[u] = (j + u) < len0 ? __uint_as_float((unsigned)(cA[u] >> 32)) : 0.f;
      wB[u] = (j + u) < len1 ? __uint_as_float((unsigned)(cB[u] >> 32)) : 0.f;
    }
    // issue all 8 gathers (addresses already register-resident)
    ushort4 xA[4], xB[4];
#pragma unroll
    for (int u = 0; u < 4; u++) {
      xA[u] = *(const ushort4*)(srcK + (size_t)(unsigned)cA[u] * 64);
      xB[u] = *(const ushort4*)(srcK + (size_t)(unsigned)cB[u] * 64);
    }
    // prefetch colval group for j+4 (overlaps the gather latency)
#pragma unroll
    for (int u = 0; u < 4; u++) {
      int ja = j + 4 + u;
      int jA = ja < l0m ? ja : l0m;
      int jB = ja < l1m ? ja : l1m;
      cA[u] = ldnt_u64(cv0 + jA);
      cB[u] = ldnt_u64(cv1 + jB);
    }
    // accumulate
#pragma unroll
    for (int u = 0; u < 4; u++) {
      p0 = fmaf(wA[u], bf2f(xA[u].x), p0);
      p1 = fmaf(wA[u], bf2f(xA[u].y), p1);
      p2 = fmaf(wA[u], bf2f(xA[u].z), p2);
      p3 = fmaf(wA[u], bf2f(xA[u].w), p3);
      r0 = fmaf(wB[u], bf2f(xB[u].x), r0);
      r1 = fmaf(wB[u], bf2f(xB[u].y), r1);
      r2 = fmaf(wB[u], bf2f(xB[u].z), r2);
      r3 = fmaf(wB[u], bf2f(xB[u].w), r3);
    }
  }

  if (va) {
    const float* e0p = (row0 < split) ? (e0U + (size_t)row0 * 64)
                                      : (e0I + (size_t)(row0 - split) * 64);
    f4 ev = ldnt_f4(e0p + k * 4);
    unsigned lo = (unsigned)f2bf(p0 + ALPHA * ev.x) | ((unsigned)f2bf(p1 + ALPHA * ev.y) << 16);
    unsigned hi = (unsigned)f2bf(p2 + ALPHA * ev.z) | ((unsigned)f2bf(p3 + ALPHA * ev.w) << 16);
    stnt_u2(dst + (size_t)row0 * 64 + k * 4, lo, hi);
  }
  if (vb) {
    const float* e0p = (row1 < split) ? (e0U + (size_t)row1 * 64)
                                      : (e0I + (size_t)(row1 - split) * 64);
    f4 ev = ldnt_f4(e0p + k * 4);
    unsigned lo = (unsigned)f2bf(r0 + ALPHA * ev.x) | ((unsigned)f2bf(r1 + ALPHA * ev.y) << 16);
    unsigned hi = (unsigned)f2bf(r2 + ALPHA * ev.z) | ((unsigned)f2bf(r3 + ALPHA * ev.w) << 16);
    stnt_u2(dst + (size_t)row1 * 64 + k * 4, lo, hi);
  }
}

__global__ __launch_bounds__(256) void k_spmm(
    const unsigned short* __restrict__ src,
    const float* __restrict__ e0U, const float* __restrict__ e0I, int split,
    const int* __restrict__ perm, const int* __restrict__ rowptrS, const int* __restrict__ lenS,
    const int2* __restrict__ colval,
    unsigned short* __restrict__ dst, int n) {
  spmm_body((int)(blockIdx.x * 256 + threadIdx.x), src, e0U, e0I, split,
            perm, rowptrS, lenS, colval, dst, n);
}

// spmm layer-2 with fused accA: acc = E0_f32[sample] + 3*bf2f(ebA[sample])
__global__ __launch_bounds__(256) void k_spmm2_acc(
    const unsigned short* __restrict__ ebA,
    const float* __restrict__ e0U, const float* __restrict__ e0I, int split,
    const int* __restrict__ perm, const int* __restrict__ rowptrS, const int* __restrict__ lenS,
    const int2* __restrict__ colval,
    unsigned short* __restrict__ ebB, int n, int spmmBlocks,
    const int* __restrict__ users, const int* __restrict__ items, int B,
    const float* __restrict__ user_emb, const float* __restrict__ item_emb,
    float* __restrict__ accU, float* __restrict__ accI) {
  if ((int)blockIdx.x < spmmBlocks) {
    spmm_body((int)(blockIdx.x * 256 + threadIdx.x), ebA, e0U, e0I, split,
              perm, rowptrS, lenS, colval, ebB, n);
  } else {
    int t = ((int)blockIdx.x - spmmBlocks) * 256 + threadIdx.x;
    int total = B * 64;
    if (t < total) {
      int b = t >> 6, d = t & 63;
      size_t idx = (size_t)users[b] * 64 + d;
      accU[t] = user_emb[idx] + 3.f * bf2f(ebA[idx]);
    } else if (t < 2 * total) {
      int t2 = t - total;
      int b = t2 >> 6, d = t2 & 63;
      int r = items[b];
      accI[t2] = item_emb[(size_t)r * 64 + d] + 3.f * bf2f(ebA[(size_t)(split + r) * 64 + d]);
    }
  }
}

// ---------------- fused layer-3 mini-SpMM + 2*E2 term (8192 sampled rows) ----------------

__global__ __launch_bounds__(256) void k_mini3(
    const int* __restrict__ users, const int* __restrict__ items, int B, int split,
    const unsigned short* __restrict__ ebB,
    const float* __restrict__ e0U, const float* __restrict__ e0I,
    const int* __restrict__ rowptr, const int* __restrict__ cnt,
    const int2* __restrict__ colval,
    float* __restrict__ accU, float* __restrict__ accI) {
  int wave = (int)((blockIdx.x * blockDim.x + threadIdx.x) >> 6);
  int lane = threadIdx.x & 63;
  int sub = lane >> 4;
  int k   = lane & 15;
  int idx = wave * 4 + sub;
  bool valid = idx < 2 * B;
  int ic = valid ? idx : 0;
  int row;
  float* accp;
  if (ic < B) { row = users[ic];             accp = accU + (size_t)ic * 64; }
  else        { row = split + items[ic - B]; accp = accI + (size_t)(ic - B) * 64; }
  int start = rowptr[row];
  int len   = valid ? cnt[row] : 0;
  int maxlen = len;
  maxlen = max(maxlen, __shfl_xor(maxlen, 16));
  maxlen = max(maxlen, __shfl_xor(maxlen, 32));
  const int2* cv = colval + start;
  const unsigned short* srcK = ebB + (size_t)k * 4;
  int lenm1 = (len > 0) ? (len - 1) : 0;

  float a0 = 0.f, a1 = 0.f, a2 = 0.f, a3 = 0.f;
  for (int j = 0; j < maxlen; j += 4) {
#pragma unroll
    for (int u = 0; u < 4; u++) {
      int jj = j + u;
      int jc = (jj < len) ? jj : lenm1;
      int2 e = cv[jc];
      float v = (jj < len) ? __int_as_float(e.y) : 0.f;
      ushort4 x = *(const ushort4*)(srcK + (size_t)e.x * 64);
      a0 = fmaf(v, bf2f(x.x), a0);
      a1 = fmaf(v, bf2f(x.y), a1);
      a2 = fmaf(v, bf2f(x.z), a2);
      a3 = fmaf(v, bf2f(x.w), a3);
    }
  }
  if (valid) {
    const float* e0p = (row < split) ? (e0U + (size_t)row * 64)
                                     : (e0I + (size_t)(row - split) * 64);
    float4 ev = *(const float4*)(e0p + k * 4);
    ushort4 x2 = *(const ushort4*)(srcK + (size_t)row * 64);  // E2[row], fused 2x term
    float4 cur = *(const float4*)(accp + k * 4);
    cur.x += a0 + ALPHA * ev.x + 2.f * bf2f(x2.x);
    cur.y += a1 + ALPHA * ev.y + 2.f * bf2f(x2.y);
    cur.z += a2 + ALPHA * ev.z + 2.f * bf2f(x2.z);
    cur.w += a3 + ALPHA * ev.w + 2.f * bf2f(x2.w);
    *(float4*)(accp + k * 4) = cur;
  }
}

__global__ void k_dot(const float* __restrict__ accU, const float* __restrict__ accI, int B,
                      float* __restrict__ out) {
  int wave = (int)((blockIdx.x * blockDim.x + threadIdx.x) >> 6);
  int lane = threadIdx.x & 63;
  if (wave >= B) return;
  float p = accU[(size_t)wave * 64 + lane] * accI[(size_t)wave * 64 + lane];
  for (int d = 32; d > 0; d >>= 1) p += __shfl_xor(p, d);
  if (lane == 0) out[wave] = p * (1.f / 16.f);  // (1/4) layer mean x (1/4) weight norm
}

// ---------------- launch ----------------

extern "C" void kernel_launch(void* const* d_in, const int* in_sizes, int n_in,
                              void* d_out, int out_size, void* d_ws, size_t ws_size,
                              hipStream_t stream) {
  const int*   users     = (const int*)d_in[0];
  const int*   items     = (const int*)d_in[1];
  const int*   rows      = (const int*)d_in[2];
  const int*   cols      = (const int*)d_in[3];
  const float* vals      = (const float*)d_in[4];
  const float* user_emb  = (const float*)d_in[5];
  const float* item_emb  = (const float*)d_in[6];
  const float* user_emb0 = (const float*)d_in[7];
  const float* item_emb0 = (const float*)d_in[8];
  float* gamma = (float*)d_out;

  int B   = in_sizes[0];
  int nnz = in_sizes[2];
  int nU  = in_sizes[5] / 64;
  int nI  = in_sizes[6] / 64;
  int N   = nU + nI;
  int nb  = (N + RPB - 1) >> BSHIFT;   // 147 buckets

  char* base = (char*)d_ws;
  unsigned short* ebIn = (unsigned short*)base;          // N*64 bf16
  unsigned short* ebA  = ebIn + (size_t)N * 64;          // N*64 bf16 (layer-1 out)
  unsigned short* ebB  = ebA  + (size_t)N * 64;          // N*64 bf16 (layer-2 out)
  uint2* pPay = (uint2*)ebA;                             // overlay: dead before layer-1 spmm
  char* p = (char*)(ebB + (size_t)N * 64);
  int2* colval  = (int2*)p;           p += ((size_t)nnz + 8) * sizeof(int2);
  int*  rowptr  = (int*)p;            p += (size_t)N * sizeof(int);
  int*  cnt     = (int*)p;            p += (size_t)N * sizeof(int);
  int*  perm    = (int*)p;            p += (size_t)N * sizeof(int);
  int*  rowptrS = (int*)p;            p += (size_t)N * sizeof(int);
  int*  lenS    = (int*)p;            p += (size_t)N * sizeof(int);
  int*  bcnt    = (int*)p;            p += MAXB * sizeof(int);
  int*  degHist = (int*)p;            p += 256 * sizeof(int);
  int*  bptr    = (int*)p;            p += (MAXB + 1) * sizeof(int);
  int*  bcur    = (int*)p;            p += MAXB * sizeof(int);
  int*  degCur  = (int*)p;            p += 256 * sizeof(int);
  float* accU   = (float*)p;          p += (size_t)B * 64 * sizeof(float);
  float* accI   = (float*)p;          p += (size_t)B * 64 * sizeof(float);

  hipMemsetAsync(bcnt, 0, (MAXB + 256) * sizeof(int), stream);  // bcnt + degHist contiguous

  const int tpb = 256;
  int nTot = N * 64;
  int convBlocks = (nTot / 4 + tpb - 1) / tpb;
  k_conv_bucket<<<512 + convBlocks, tpb, 0, stream>>>(rows, nnz, bcnt,
                                                      user_emb, item_emb, nU * 64, nTot, ebIn);
  k_scan_buckets<<<1, 256, 0, stream>>>(bcnt, nb, bptr, bcur);
  k_partition<<<(nnz + CHUNK - 1) / CHUNK, tpb, 0, stream>>>(rows, cols, vals, nnz, bcur, pPay);
  k_build_csr<<<nb, tpb, 0, stream>>>(bptr, pPay, N, rowptr, cnt, colval, degHist);
  k_degscan<<<1, 256, 0, stream>>>(degHist, degCur, colval, nnz);
  k_permute<<<(N + 1023) / 1024, tpb, 0, stream>>>(rowptr, cnt, N, degCur, perm, rowptrS, lenS);

  // 32 rows per 256-thread block (4 waves x 4 quarters x 2 rows)
  int spmmBlocks = (N + 31) / 32;
  int accBlocks = (2 * B * 64 + tpb - 1) / tpb;

  // layer 1: src = ebIn, dst = ebA (pPay dead from here)
  k_spmm<<<spmmBlocks, tpb, 0, stream>>>(ebIn, user_emb0, item_emb0, nU,
                                         perm, rowptrS, lenS, colval, ebA, N);

  // layer 2 + fused accA (E0 + 3*E1 at sampled rows)
  k_spmm2_acc<<<spmmBlocks + accBlocks, tpb, 0, stream>>>(ebA, user_emb0, item_emb0, nU,
                                                          perm, rowptrS, lenS, colval, ebB, N,
                                                          spmmBlocks, users, items, B,
                                                          user_emb, item_emb, accU, accI);

  // layer 3 sampled rows + fused 2*E2 term
  int mBlocks = (2 * B + 15) / 16;
  k_mini3<<<mBlocks, tpb, 0, stream>>>(users, items, B, nU, ebB,
                                       user_emb0, item_emb0,
                                       rowptr, cnt, colval, accU, accI);

  k_dot<<<(B * 64 + tpb - 1) / tpb, tpb, 0, stream>>>(accU, accI, B, gamma);
}

// Round 2
// 664.180 us; speedup vs baseline: 1.0812x; 1.0812x over previous
//
#include <hip/hip_runtime.h>

#define ALPHA 0.5f
#define BSHIFT 11                // 2048 rows per bucket
#define RPB 2048
#define MAXB 256                 // >= nBuckets (147)
#define CHUNK 8192               // edges per partition block

// ---------------- bf16 helpers ----------------

__device__ __forceinline__ float bf2f(unsigned short u) {
  return __uint_as_float((unsigned)u << 16);
}
__device__ __forceinline__ unsigned short f2bf(float f) {
  unsigned u = __float_as_uint(f);
  u += 0x7fffu + ((u >> 16) & 1u);   // round-to-nearest-even
  return (unsigned short)(u >> 16);
}

// ---------------- fused: bucket counts (blocks 0..511) + f32->bf16 convert ----------------

__global__ __launch_bounds__(256) void k_conv_bucket(
    const int* __restrict__ rows, int nnz, int* __restrict__ bcnt,
    const float* __restrict__ uE, const float* __restrict__ iE,
    int nU64, int nTot, unsigned short* __restrict__ out) {
  __shared__ int lcnt[MAXB];
  int t = threadIdx.x;
  if (blockIdx.x < 512) {
    if (t < MAXB) lcnt[t] = 0;
    __syncthreads();
    int stride = 512 * 256;
    for (int e = blockIdx.x * 256 + t; e < nnz; e += stride)
      atomicAdd(&lcnt[rows[e] >> BSHIFT], 1);
    __syncthreads();
    if (t < MAXB) {
      int c = lcnt[t];
      if (c) atomicAdd(&bcnt[t], c);
    }
  } else {
    int i = ((int)(blockIdx.x - 512) * 256 + t) * 4;
    if (i >= nTot) return;
    const float* src = (i < nU64) ? (uE + i) : (iE + (i - nU64));
    float4 v = *(const float4*)src;
    ushort4 o;
    o.x = f2bf(v.x); o.y = f2bf(v.y); o.z = f2bf(v.z); o.w = f2bf(v.w);
    *(ushort4*)(out + i) = o;
  }
}

// ---------------- scan bucket counts -> bptr, bcur ----------------

__global__ void k_scan_buckets(const int* __restrict__ bcnt, int nb,
                               int* __restrict__ bptr, int* __restrict__ bcur) {
  __shared__ int s[256];
  int t = threadIdx.x;
  int v = (t < nb) ? bcnt[t] : 0;
  s[t] = v; __syncthreads();
  for (int d = 1; d < 256; d <<= 1) {
    int x = (t >= d) ? s[t - d] : 0;
    __syncthreads();
    s[t] += x;
    __syncthreads();
  }
  if (t < nb) {
    int excl = s[t] - v;
    bptr[t] = excl;
    bcur[t] = excl;
  }
  if (t == 0) bptr[nb] = s[255];   // total
}

// ---------------- partition edges into buckets (packed 8B payload) ----------------

__global__ __launch_bounds__(256) void k_partition(
    const int* __restrict__ rows, const int* __restrict__ cols, const float* __restrict__ vals,
    int nnz, int* __restrict__ bcur, uint2* __restrict__ pPay) {
  __shared__ int lcnt[MAXB];
  __shared__ int lbase[MAXB];
  int t = threadIdx.x;
  if (t < MAXB) lcnt[t] = 0;
  __syncthreads();
  int base = blockIdx.x * CHUNK;
  int end = nnz < base + CHUNK ? nnz : base + CHUNK;
  for (int e = base + t; e < end; e += 256)
    atomicAdd(&lcnt[rows[e] >> BSHIFT], 1);
  __syncthreads();
  if (t < MAXB) {
    int c = lcnt[t];
    lbase[t] = c ? atomicAdd(&bcur[t], c) : 0;
    lcnt[t] = 0;
  }
  __syncthreads();
  for (int e = base + t; e < end; e += 256) {
    int r = rows[e];
    int b = r >> BSHIFT;
    int p = lbase[b] + atomicAdd(&lcnt[b], 1);
    uint2 pay;
    pay.x = ((unsigned)(r & (RPB - 1)) << 20) | (unsigned)cols[e];
    pay.y = __float_as_uint(vals[e]);
    pPay[p] = pay;
  }
}

// ---------------- per-bucket CSR build + degree histogram ----------------

__global__ __launch_bounds__(256) void k_build_csr(
    const int* __restrict__ bptr, const uint2* __restrict__ pPay, int N,
    int* __restrict__ rowptr, int* __restrict__ cnt, int2* __restrict__ colval,
    int* __restrict__ degHist) {
  __shared__ int lcnt[RPB];        // 8 KB: counts -> cursors
  __shared__ int scanbuf[256];
  __shared__ int ldeg[256];
  int t = threadIdx.x;
  int b = blockIdx.x;
  int r0 = b << BSHIFT;
  int rCount = N - r0; if (rCount > RPB) rCount = RPB;
  int eBeg = bptr[b], eEnd = bptr[b + 1];

  for (int r = t; r < RPB; r += 256) lcnt[r] = 0;
  ldeg[t] = 0;
  __syncthreads();
  for (int e = eBeg + t; e < eEnd; e += 256)
    atomicAdd(&lcnt[pPay[e].x >> 20], 1);
  __syncthreads();
  for (int r = t; r < rCount; r += 256) {
    int c = lcnt[r];
    cnt[r0 + r] = c;
    atomicAdd(&ldeg[c < 255 ? c : 255], 1);
  }
  int v8[8]; int s = 0;
#pragma unroll
  for (int k = 0; k < 8; k++) {
    int x = lcnt[8 * t + k];
    v8[k] = s; s += x;
  }
  scanbuf[t] = s; __syncthreads();
  for (int d = 1; d < 256; d <<= 1) {
    int x = (t >= d) ? scanbuf[t - d] : 0;
    __syncthreads();
    scanbuf[t] += x;
    __syncthreads();
  }
  int blockExcl = scanbuf[t] - s;
#pragma unroll
  for (int k = 0; k < 8; k++) lcnt[8 * t + k] = blockExcl + v8[k];
  __syncthreads();
  if (ldeg[t]) atomicAdd(&degHist[t], ldeg[t]);
  for (int r = t; r < rCount; r += 256) rowptr[r0 + r] = eBeg + lcnt[r];
  __syncthreads();
  for (int e = eBeg + t; e < eEnd; e += 256) {
    uint2 pay = pPay[e];
    int r = (int)(pay.x >> 20);
    int p = eBeg + atomicAdd(&lcnt[r], 1);
    int2 cv; cv.x = (int)(pay.x & 0xFFFFFu); cv.y = (int)pay.y;
    colval[p] = cv;
  }
}

// ---------------- degree-bin scan (1 block) + colval pad init ----------------

__global__ void k_degscan(const int* __restrict__ degHist, int* __restrict__ degCur,
                          int2* __restrict__ colval, int nnz) {
  __shared__ int s[256];
  int t = threadIdx.x;
  int v = degHist[t];
  s[t] = v; __syncthreads();
  for (int d = 1; d < 256; d <<= 1) {
    int x = (t >= d) ? s[t - d] : 0;
    __syncthreads();
    s[t] += x;
    __syncthreads();
  }
  degCur[t] = s[t] - v;   // exclusive
  if (t < 8) { int2 z; z.x = 0; z.y = 0; colval[nnz + t] = z; }
}

// ---------------- permute rows into degree-sorted order ----------------

__global__ __launch_bounds__(256) void k_permute(
    const int* __restrict__ rowptr, const int* __restrict__ cnt, int N,
    int* __restrict__ degCur,
    int* __restrict__ perm, int* __restrict__ rowptrS, int* __restrict__ lenS) {
  __shared__ int lcnt[256];
  __shared__ int lbase[256];
  int t = threadIdx.x;
  lcnt[t] = 0;
  __syncthreads();
  int base = blockIdx.x * 1024;
  int end = N < base + 1024 ? N : base + 1024;
  for (int r = base + t; r < end; r += 256) {
    int c = cnt[r];
    atomicAdd(&lcnt[c < 255 ? c : 255], 1);
  }
  __syncthreads();
  {
    int c = lcnt[t];
    lbase[t] = c ? atomicAdd(&degCur[t], c) : 0;
    lcnt[t] = 0;
  }
  __syncthreads();
  for (int r = base + t; r < end; r += 256) {
    int c = cnt[r];
    int bin = c < 255 ? c : 255;
    int pos = lbase[bin] + atomicAdd(&lcnt[bin], 1);
    perm[pos] = r;
    rowptrS[pos] = rowptr[r];
    lenS[pos] = c;
  }
}

// ---------------- SpMM core: quarter-wave owns 2 degree-adjacent rows ----------------
// Software-pipelined: colval group for iteration j+4 is prefetched while the
// 8 gathers for iteration j are in flight. Plain (cached) loads/stores only —
// nt hints on the embedding stores poisoned the next layer's gather source
// (round-1 post-mortem: FETCH +73MB).

__device__ __forceinline__ void spmm_body(
    int gtid,
    const unsigned short* __restrict__ src,
    const float* __restrict__ e0U, const float* __restrict__ e0I, int split,
    const int* __restrict__ perm, const int* __restrict__ rowptrS, const int* __restrict__ lenS,
    const int2* __restrict__ colval,
    unsigned short* __restrict__ dst, int n) {
  int wave = gtid >> 6;
  int lane = gtid & 63;
  int sub = lane >> 4;
  int k   = lane & 15;
  int q = wave * 4 + sub;
  int s0 = 2 * q, s1 = 2 * q + 1;
  bool va = s0 < n, vb = s1 < n;
  int i0 = va ? s0 : 0, i1 = vb ? s1 : 0;
  int row0 = perm[i0], row1 = perm[i1];
  int st0 = rowptrS[i0], st1 = rowptrS[i1];
  int len0 = va ? lenS[i0] : 0, len1 = vb ? lenS[i1] : 0;
  const int2* cv0 = colval + st0;
  const int2* cv1 = colval + st1;
  const unsigned short* srcK = src + (size_t)k * 4;
  int l0m = len0 > 0 ? len0 - 1 : 0;
  int l1m = len1 > 0 ? len1 - 1 : 0;
  int mx = max(len0, len1);

  float p0 = 0.f, p1 = 0.f, p2 = 0.f, p3 = 0.f;     // row0 acc
  float r0 = 0.f, r1 = 0.f, r2 = 0.f, r3 = 0.f;     // row1 acc

  // preload colval group for j = 0..3 (packed col | weight in 8B)
  unsigned long long cA[4], cB[4];
#pragma unroll
  for (int u = 0; u < 4; u++) {
    int jA = u < l0m ? u : l0m;
    int jB = u < l1m ? u : l1m;
    cA[u] = *(const unsigned long long*)(cv0 + jA);
    cB[u] = *(const unsigned long long*)(cv1 + jB);
  }

  for (int j = 0; j < mx; j += 4) {
    // extract weights for the current group before the registers are reloaded
    float wA[4], wB[4];
#pragma unroll
    for (int u = 0; u < 4; u++) {
      wA[u] = (j + u) < len0 ? __uint_as_float((unsigned)(cA[u] >> 32)) : 0.f;
      wB[u] = (j + u) < len1 ? __uint_as_float((unsigned)(cB[u] >> 32)) : 0.f;
    }
    // issue all 8 gathers (addresses already register-resident)
    ushort4 xA[4], xB[4];
#pragma unroll
    for (int u = 0; u < 4; u++) {
      xA[u] = *(const ushort4*)(srcK + (size_t)(unsigned)cA[u] * 64);
      xB[u] = *(const ushort4*)(srcK + (size_t)(unsigned)cB[u] * 64);
    }
    // prefetch colval group for j+4 (overlaps the gather latency)
#pragma unroll
    for (int u = 0; u < 4; u++) {
      int ja = j + 4 + u;
      int jA = ja < l0m ? ja : l0m;
      int jB = ja < l1m ? ja : l1m;
      cA[u] = *(const unsigned long long*)(cv0 + jA);
      cB[u] = *(const unsigned long long*)(cv1 + jB);
    }
    // accumulate
#pragma unroll
    for (int u = 0; u < 4; u++) {
      p0 = fmaf(wA[u], bf2f(xA[u].x), p0);
      p1 = fmaf(wA[u], bf2f(xA[u].y), p1);
      p2 = fmaf(wA[u], bf2f(xA[u].z), p2);
      p3 = fmaf(wA[u], bf2f(xA[u].w), p3);
      r0 = fmaf(wB[u], bf2f(xB[u].x), r0);
      r1 = fmaf(wB[u], bf2f(xB[u].y), r1);
      r2 = fmaf(wB[u], bf2f(xB[u].z), r2);
      r3 = fmaf(wB[u], bf2f(xB[u].w), r3);
    }
  }

  if (va) {
    const float* e0p = (row0 < split) ? (e0U + (size_t)row0 * 64)
                                      : (e0I + (size_t)(row0 - split) * 64);
    float4 ev = *(const float4*)(e0p + k * 4);
    ushort4 o;
    o.x = f2bf(p0 + ALPHA * ev.x);
    o.y = f2bf(p1 + ALPHA * ev.y);
    o.z = f2bf(p2 + ALPHA * ev.z);
    o.w = f2bf(p3 + ALPHA * ev.w);
    *(ushort4*)(dst + (size_t)row0 * 64 + k * 4) = o;
  }
  if (vb) {
    const float* e0p = (row1 < split) ? (e0U + (size_t)row1 * 64)
                                      : (e0I + (size_t)(row1 - split) * 64);
    float4 ev = *(const float4*)(e0p + k * 4);
    ushort4 o;
    o.x = f2bf(r0 + ALPHA * ev.x);
    o.y = f2bf(r1 + ALPHA * ev.y);
    o.z = f2bf(r2 + ALPHA * ev.z);
    o.w = f2bf(r3 + ALPHA * ev.w);
    *(ushort4*)(dst + (size_t)row1 * 64 + k * 4) = o;
  }
}

__global__ __launch_bounds__(256) void k_spmm(
    const unsigned short* __restrict__ src,
    const float* __restrict__ e0U, const float* __restrict__ e0I, int split,
    const int* __restrict__ perm, const int* __restrict__ rowptrS, const int* __restrict__ lenS,
    const int2* __restrict__ colval,
    unsigned short* __restrict__ dst, int n) {
  spmm_body((int)(blockIdx.x * 256 + threadIdx.x), src, e0U, e0I, split,
            perm, rowptrS, lenS, colval, dst, n);
}

// spmm layer-2 with fused accA: acc = E0_f32[sample] + 3*bf2f(ebA[sample])
__global__ __launch_bounds__(256) void k_spmm2_acc(
    const unsigned short* __restrict__ ebA,
    const float* __restrict__ e0U, const float* __restrict__ e0I, int split,
    const int* __restrict__ perm, const int* __restrict__ rowptrS, const int* __restrict__ lenS,
    const int2* __restrict__ colval,
    unsigned short* __restrict__ ebB, int n, int spmmBlocks,
    const int* __restrict__ users, const int* __restrict__ items, int B,
    const float* __restrict__ user_emb, const float* __restrict__ item_emb,
    float* __restrict__ accU, float* __restrict__ accI) {
  if ((int)blockIdx.x < spmmBlocks) {
    spmm_body((int)(blockIdx.x * 256 + threadIdx.x), ebA, e0U, e0I, split,
              perm, rowptrS, lenS, colval, ebB, n);
  } else {
    int t = ((int)blockIdx.x - spmmBlocks) * 256 + threadIdx.x;
    int total = B * 64;
    if (t < total) {
      int b = t >> 6, d = t & 63;
      size_t idx = (size_t)users[b] * 64 + d;
      accU[t] = user_emb[idx] + 3.f * bf2f(ebA[idx]);
    } else if (t < 2 * total) {
      int t2 = t - total;
      int b = t2 >> 6, d = t2 & 63;
      int r = items[b];
      accI[t2] = item_emb[(size_t)r * 64 + d] + 3.f * bf2f(ebA[(size_t)(split + r) * 64 + d]);
    }
  }
}

// ---------------- fused layer-3 mini-SpMM + 2*E2 term (8192 sampled rows) ----------------

__global__ __launch_bounds__(256) void k_mini3(
    const int* __restrict__ users, const int* __restrict__ items, int B, int split,
    const unsigned short* __restrict__ ebB,
    const float* __restrict__ e0U, const float* __restrict__ e0I,
    const int* __restrict__ rowptr, const int* __restrict__ cnt,
    const int2* __restrict__ colval,
    float* __restrict__ accU, float* __restrict__ accI) {
  int wave = (int)((blockIdx.x * blockDim.x + threadIdx.x) >> 6);
  int lane = threadIdx.x & 63;
  int sub = lane >> 4;
  int k   = lane & 15;
  int idx = wave * 4 + sub;
  bool valid = idx < 2 * B;
  int ic = valid ? idx : 0;
  int row;
  float* accp;
  if (ic < B) { row = users[ic];             accp = accU + (size_t)ic * 64; }
  else        { row = split + items[ic - B]; accp = accI + (size_t)(ic - B) * 64; }
  int start = rowptr[row];
  int len   = valid ? cnt[row] : 0;
  int maxlen = len;
  maxlen = max(maxlen, __shfl_xor(maxlen, 16));
  maxlen = max(maxlen, __shfl_xor(maxlen, 32));
  const int2* cv = colval + start;
  const unsigned short* srcK = ebB + (size_t)k * 4;
  int lenm1 = (len > 0) ? (len - 1) : 0;

  float a0 = 0.f, a1 = 0.f, a2 = 0.f, a3 = 0.f;
  for (int j = 0; j < maxlen; j += 4) {
#pragma unroll
    for (int u = 0; u < 4; u++) {
      int jj = j + u;
      int jc = (jj < len) ? jj : lenm1;
      int2 e = cv[jc];
      float v = (jj < len) ? __int_as_float(e.y) : 0.f;
      ushort4 x = *(const ushort4*)(srcK + (size_t)e.x * 64);
      a0 = fmaf(v, bf2f(x.x), a0);
      a1 = fmaf(v, bf2f(x.y), a1);
      a2 = fmaf(v, bf2f(x.z), a2);
      a3 = fmaf(v, bf2f(x.w), a3);
    }
  }
  if (valid) {
    const float* e0p = (row < split) ? (e0U + (size_t)row * 64)
                                     : (e0I + (size_t)(row - split) * 64);
    float4 ev = *(const float4*)(e0p + k * 4);
    ushort4 x2 = *(const ushort4*)(srcK + (size_t)row * 64);  // E2[row], fused 2x term
    float4 cur = *(const float4*)(accp + k * 4);
    cur.x += a0 + ALPHA * ev.x + 2.f * bf2f(x2.x);
    cur.y += a1 + ALPHA * ev.y + 2.f * bf2f(x2.y);
    cur.z += a2 + ALPHA * ev.z + 2.f * bf2f(x2.z);
    cur.w += a3 + ALPHA * ev.w + 2.f * bf2f(x2.w);
    *(float4*)(accp + k * 4) = cur;
  }
}

__global__ void k_dot(const float* __restrict__ accU, const float* __restrict__ accI, int B,
                      float* __restrict__ out) {
  int wave = (int)((blockIdx.x * blockDim.x + threadIdx.x) >> 6);
  int lane = threadIdx.x & 63;
  if (wave >= B) return;
  float p = accU[(size_t)wave * 64 + lane] * accI[(size_t)wave * 64 + lane];
  for (int d = 32; d > 0; d >>= 1) p += __shfl_xor(p, d);
  if (lane == 0) out[wave] = p * (1.f / 16.f);  // (1/4) layer mean x (1/4) weight norm
}

// ---------------- launch ----------------

extern "C" void kernel_launch(void* const* d_in, const int* in_sizes, int n_in,
                              void* d_out, int out_size, void* d_ws, size_t ws_size,
                              hipStream_t stream) {
  const int*   users     = (const int*)d_in[0];
  const int*   items     = (const int*)d_in[1];
  const int*   rows      = (const int*)d_in[2];
  const int*   cols      = (const int*)d_in[3];
  const float* vals      = (const float*)d_in[4];
  const float* user_emb  = (const float*)d_in[5];
  const float* item_emb  = (const float*)d_in[6];
  const float* user_emb0 = (const float*)d_in[7];
  const float* item_emb0 = (const float*)d_in[8];
  float* gamma = (float*)d_out;

  int B   = in_sizes[0];
  int nnz = in_sizes[2];
  int nU  = in_sizes[5] / 64;
  int nI  = in_sizes[6] / 64;
  int N   = nU + nI;
  int nb  = (N + RPB - 1) >> BSHIFT;   // 147 buckets

  char* base = (char*)d_ws;
  unsigned short* ebIn = (unsigned short*)base;          // N*64 bf16
  unsigned short* ebA  = ebIn + (size_t)N * 64;          // N*64 bf16 (layer-1 out)
  unsigned short* ebB  = ebA  + (size_t)N * 64;          // N*64 bf16 (layer-2 out)
  uint2* pPay = (uint2*)ebA;                             // overlay: dead before layer-1 spmm
  char* p = (char*)(ebB + (size_t)N * 64);
  int2* colval  = (int2*)p;           p += ((size_t)nnz + 8) * sizeof(int2);
  int*  rowptr  = (int*)p;            p += (size_t)N * sizeof(int);
  int*  cnt     = (int*)p;            p += (size_t)N * sizeof(int);
  int*  perm    = (int*)p;            p += (size_t)N * sizeof(int);
  int*  rowptrS = (int*)p;            p += (size_t)N * sizeof(int);
  int*  lenS    = (int*)p;            p += (size_t)N * sizeof(int);
  int*  bcnt    = (int*)p;            p += MAXB * sizeof(int);
  int*  degHist = (int*)p;            p += 256 * sizeof(int);
  int*  bptr    = (int*)p;            p += (MAXB + 1) * sizeof(int);
  int*  bcur    = (int*)p;            p += MAXB * sizeof(int);
  int*  degCur  = (int*)p;            p += 256 * sizeof(int);
  float* accU   = (float*)p;          p += (size_t)B * 64 * sizeof(float);
  float* accI   = (float*)p;          p += (size_t)B * 64 * sizeof(float);

  hipMemsetAsync(bcnt, 0, (MAXB + 256) * sizeof(int), stream);  // bcnt + degHist contiguous

  const int tpb = 256;
  int nTot = N * 64;
  int convBlocks = (nTot / 4 + tpb - 1) / tpb;
  k_conv_bucket<<<512 + convBlocks, tpb, 0, stream>>>(rows, nnz, bcnt,
                                                      user_emb, item_emb, nU * 64, nTot, ebIn);
  k_scan_buckets<<<1, 256, 0, stream>>>(bcnt, nb, bptr, bcur);
  k_partition<<<(nnz + CHUNK - 1) / CHUNK, tpb, 0, stream>>>(rows, cols, vals, nnz, bcur, pPay);
  k_build_csr<<<nb, tpb, 0, stream>>>(bptr, pPay, N, rowptr, cnt, colval, degHist);
  k_degscan<<<1, 256, 0, stream>>>(degHist, degCur, colval, nnz);
  k_permute<<<(N + 1023) / 1024, tpb, 0, stream>>>(rowptr, cnt, N, degCur, perm, rowptrS, lenS);

  // 32 rows per 256-thread block (4 waves x 4 quarters x 2 rows)
  int spmmBlocks = (N + 31) / 32;
  int accBlocks = (2 * B * 64 + tpb - 1) / tpb;

  // layer 1: src = ebIn, dst = ebA (pPay dead from here)
  k_spmm<<<spmmBlocks, tpb, 0, stream>>>(ebIn, user_emb0, item_emb0, nU,
                                         perm, rowptrS, lenS, colval, ebA, N);

  // layer 2 + fused accA (E0 + 3*E1 at sampled rows)
  k_spmm2_acc<<<spmmBlocks + accBlocks, tpb, 0, stream>>>(ebA, user_emb0, item_emb0, nU,
                                                          perm, rowptrS, lenS, colval, ebB, N,
                                                          spmmBlocks, users, items, B,
                                                          user_emb, item_emb, accU, accI);

  // layer 3 sampled rows + fused 2*E2 term
  int mBlocks = (2 * B + 15) / 16;
  k_mini3<<<mBlocks, tpb, 0, stream>>>(users, items, B, nU, ebB,
                                       user_emb0, item_emb0,
                                       rowptr, cnt, colval, accU, accI);

  k_dot<<<(B * 64 + tpb - 1) / tpb, tpb, 0, stream>>>(accU, accI, B, gamma);
}

// Round 3
// 661.113 us; speedup vs baseline: 1.0862x; 1.0046x over previous
//
#include <hip/hip_runtime.h>

#define ALPHA 0.5f
#define BSHIFT 9                 // 512 rows per bucket (4x blocks vs BSHIFT=11)
#define RPB 512
#define MAXB 1024                // >= nBuckets (586)
#define CHUNK 8192               // edges per partition block

// ---------------- bf16 helpers ----------------

__device__ __forceinline__ float bf2f(unsigned short u) {
  return __uint_as_float((unsigned)u << 16);
}
__device__ __forceinline__ unsigned short f2bf(float f) {
  unsigned u = __float_as_uint(f);
  u += 0x7fffu + ((u >> 16) & 1u);   // round-to-nearest-even
  return (unsigned short)(u >> 16);
}

// ---------------- fused: bucket counts (blocks 0..511) + f32->bf16 convert ----------------

__global__ __launch_bounds__(256) void k_conv_bucket(
    const int* __restrict__ rows, int nnz, int* __restrict__ bcnt,
    const float* __restrict__ uE, const float* __restrict__ iE,
    int nU64, int nTot, unsigned short* __restrict__ out) {
  __shared__ int lcnt[MAXB];
  int t = threadIdx.x;
  if (blockIdx.x < 512) {
    for (int i = t; i < MAXB; i += 256) lcnt[i] = 0;
    __syncthreads();
    int stride = 512 * 256;
    for (int e = blockIdx.x * 256 + t; e < nnz; e += stride)
      atomicAdd(&lcnt[rows[e] >> BSHIFT], 1);
    __syncthreads();
    for (int i = t; i < MAXB; i += 256) {
      int c = lcnt[i];
      if (c) atomicAdd(&bcnt[i], c);
    }
  } else {
    int i = ((int)(blockIdx.x - 512) * 256 + t) * 4;
    if (i >= nTot) return;
    const float* src = (i < nU64) ? (uE + i) : (iE + (i - nU64));
    float4 v = *(const float4*)src;
    ushort4 o;
    o.x = f2bf(v.x); o.y = f2bf(v.y); o.z = f2bf(v.z); o.w = f2bf(v.w);
    *(ushort4*)(out + i) = o;
  }
}

// ---------------- scan bucket counts -> bptr, bcur (256 threads x 4 elems) ----------------

__global__ void k_scan_buckets(const int* __restrict__ bcnt, int nb,
                               int* __restrict__ bptr, int* __restrict__ bcur) {
  __shared__ int s[256];
  int t = threadIdx.x;
  int v[4]; int sum = 0;
#pragma unroll
  for (int u = 0; u < 4; u++) {
    int i = t * 4 + u;
    v[u] = (i < nb) ? bcnt[i] : 0;
    sum += v[u];
  }
  s[t] = sum; __syncthreads();
  for (int d = 1; d < 256; d <<= 1) {
    int x = (t >= d) ? s[t - d] : 0;
    __syncthreads();
    s[t] += x;
    __syncthreads();
  }
  int excl = s[t] - sum;
#pragma unroll
  for (int u = 0; u < 4; u++) {
    int i = t * 4 + u;
    if (i < nb) { bptr[i] = excl; bcur[i] = excl; }
    excl += v[u];
  }
  if (t == 0) bptr[nb] = s[255];   // total
}

// ---------------- partition edges into buckets (packed 8B payload) ----------------
// pay.x = rowLocal(9b) << 20 | col(19b)

__global__ __launch_bounds__(256) void k_partition(
    const int* __restrict__ rows, const int* __restrict__ cols, const float* __restrict__ vals,
    int nnz, int* __restrict__ bcur, uint2* __restrict__ pPay) {
  __shared__ int lcnt[MAXB];
  __shared__ int lbase[MAXB];
  int t = threadIdx.x;
  for (int i = t; i < MAXB; i += 256) lcnt[i] = 0;
  __syncthreads();
  int base = blockIdx.x * CHUNK;
  int end = nnz < base + CHUNK ? nnz : base + CHUNK;
  for (int e = base + t; e < end; e += 256)
    atomicAdd(&lcnt[rows[e] >> BSHIFT], 1);
  __syncthreads();
  for (int i = t; i < MAXB; i += 256) {
    int c = lcnt[i];
    lbase[i] = c ? atomicAdd(&bcur[i], c) : 0;
    lcnt[i] = 0;
  }
  __syncthreads();
  for (int e = base + t; e < end; e += 256) {
    int r = rows[e];
    int b = r >> BSHIFT;
    int p = lbase[b] + atomicAdd(&lcnt[b], 1);
    uint2 pay;
    pay.x = ((unsigned)(r & (RPB - 1)) << 20) | (unsigned)cols[e];
    pay.y = __float_as_uint(vals[e]);
    pPay[p] = pay;
  }
}

// ---------------- per-bucket CSR build + degree histogram ----------------

__global__ __launch_bounds__(256) void k_build_csr(
    const int* __restrict__ bptr, const uint2* __restrict__ pPay, int N,
    int* __restrict__ rowptr, int* __restrict__ cnt, int2* __restrict__ colval,
    int* __restrict__ degHist) {
  __shared__ int lcnt[RPB];        // 2 KB: counts -> cursors
  __shared__ int scanbuf[256];
  __shared__ int ldeg[256];
  int t = threadIdx.x;
  int b = blockIdx.x;
  int r0 = b << BSHIFT;
  int rCount = N - r0; if (rCount > RPB) rCount = RPB;
  int eBeg = bptr[b], eEnd = bptr[b + 1];

  for (int r = t; r < RPB; r += 256) lcnt[r] = 0;
  ldeg[t] = 0;
  __syncthreads();
  for (int e = eBeg + t; e < eEnd; e += 256)
    atomicAdd(&lcnt[pPay[e].x >> 20], 1);
  __syncthreads();
  for (int r = t; r < rCount; r += 256) {
    int c = lcnt[r];
    cnt[r0 + r] = c;
    atomicAdd(&ldeg[c < 255 ? c : 255], 1);
  }
  int v2[2]; int s = 0;
#pragma unroll
  for (int k = 0; k < 2; k++) {
    int x = lcnt[2 * t + k];
    v2[k] = s; s += x;
  }
  scanbuf[t] = s; __syncthreads();
  for (int d = 1; d < 256; d <<= 1) {
    int x = (t >= d) ? scanbuf[t - d] : 0;
    __syncthreads();
    scanbuf[t] += x;
    __syncthreads();
  }
  int blockExcl = scanbuf[t] - s;
#pragma unroll
  for (int k = 0; k < 2; k++) lcnt[2 * t + k] = blockExcl + v2[k];
  __syncthreads();
  if (ldeg[t]) atomicAdd(&degHist[t], ldeg[t]);
  for (int r = t; r < rCount; r += 256) rowptr[r0 + r] = eBeg + lcnt[r];
  __syncthreads();
  for (int e = eBeg + t; e < eEnd; e += 256) {
    uint2 pay = pPay[e];
    int r = (int)(pay.x >> 20);
    int p = eBeg + atomicAdd(&lcnt[r], 1);
    int2 cv; cv.x = (int)(pay.x & 0xFFFFFu); cv.y = (int)pay.y;
    colval[p] = cv;
  }
}

// ---------------- degree-bin scan (1 block) + colval pad init ----------------

__global__ void k_degscan(const int* __restrict__ degHist, int* __restrict__ degCur,
                          int2* __restrict__ colval, int nnz) {
  __shared__ int s[256];
  int t = threadIdx.x;
  int v = degHist[t];
  s[t] = v; __syncthreads();
  for (int d = 1; d < 256; d <<= 1) {
    int x = (t >= d) ? s[t - d] : 0;
    __syncthreads();
    s[t] += x;
    __syncthreads();
  }
  degCur[t] = s[t] - v;   // exclusive
  if (t < 8) { int2 z; z.x = 0; z.y = 0; colval[nnz + t] = z; }
}

// ---------------- permute rows into degree-sorted order ----------------

__global__ __launch_bounds__(256) void k_permute(
    const int* __restrict__ rowptr, const int* __restrict__ cnt, int N,
    int* __restrict__ degCur,
    int* __restrict__ perm, int* __restrict__ rowptrS, int* __restrict__ lenS) {
  __shared__ int lcnt[256];
  __shared__ int lbase[256];
  int t = threadIdx.x;
  lcnt[t] = 0;
  __syncthreads();
  int base = blockIdx.x * 512;
  int end = N < base + 512 ? N : base + 512;
  for (int r = base + t; r < end; r += 256) {
    int c = cnt[r];
    atomicAdd(&lcnt[c < 255 ? c : 255], 1);
  }
  __syncthreads();
  {
    int c = lcnt[t];
    lbase[t] = c ? atomicAdd(&degCur[t], c) : 0;
    lcnt[t] = 0;
  }
  __syncthreads();
  for (int r = base + t; r < end; r += 256) {
    int c = cnt[r];
    int bin = c < 255 ? c : 255;
    int pos = lbase[bin] + atomicAdd(&lcnt[bin], 1);
    perm[pos] = r;
    rowptrS[pos] = rowptr[r];
    lenS[pos] = c;
  }
}

// ---------------- SpMM core: quarter-wave owns 2 degree-adjacent rows ----------------
// lane = 16*sub + k; quarter sub owns perm slots 2*(wave*4+sub)(+1); lane = dims 4k..4k+3.
// (round-0 proven body; pipeline/unroll variants measured slower in r1/r2)

__device__ __forceinline__ void spmm_body(
    int gtid,
    const unsigned short* __restrict__ src,
    const float* __restrict__ e0U, const float* __restrict__ e0I, int split,
    const int* __restrict__ perm, const int* __restrict__ rowptrS, const int* __restrict__ lenS,
    const int2* __restrict__ colval,
    unsigned short* __restrict__ dst, int n) {
  int wave = gtid >> 6;
  int lane = gtid & 63;
  int sub = lane >> 4;
  int k   = lane & 15;
  int q = wave * 4 + sub;
  int s0 = 2 * q, s1 = 2 * q + 1;
  bool va = s0 < n, vb = s1 < n;
  int i0 = va ? s0 : 0, i1 = vb ? s1 : 0;
  int row0 = perm[i0], row1 = perm[i1];
  int st0 = rowptrS[i0], st1 = rowptrS[i1];
  int len0 = va ? lenS[i0] : 0, len1 = vb ? lenS[i1] : 0;
  const int2* cv0 = colval + st0;
  const int2* cv1 = colval + st1;
  const unsigned short* srcK = src + (size_t)k * 4;
  int l0m = len0 > 0 ? len0 - 1 : 0;
  int l1m = len1 > 0 ? len1 - 1 : 0;
  int mx = max(len0, len1);

  float p0 = 0.f, p1 = 0.f, p2 = 0.f, p3 = 0.f;   // row0
  float r0a = 0.f, r1a = 0.f, r2a = 0.f, r3a = 0.f; // row1
  for (int j = 0; j < mx; j += 2) {
    int ja = j, jb = j + 1;
    int j0a = ja < l0m ? ja : l0m, j0b = jb < l0m ? jb : l0m;
    int j1a = ja < l1m ? ja : l1m, j1b = jb < l1m ? jb : l1m;
    int2 e0a = cv0[j0a];
    int2 e0b = cv0[j0b];
    int2 e1a = cv1[j1a];
    int2 e1b = cv1[j1b];
    ushort4 x0a = *(const ushort4*)(srcK + (size_t)e0a.x * 64);
    ushort4 x0b = *(const ushort4*)(srcK + (size_t)e0b.x * 64);
    ushort4 x1a = *(const ushort4*)(srcK + (size_t)e1a.x * 64);
    ushort4 x1b = *(const ushort4*)(srcK + (size_t)e1b.x * 64);
    float w0a = ja < len0 ? __int_as_float(e0a.y) : 0.f;
    float w0b = jb < len0 ? __int_as_float(e0b.y) : 0.f;
    float w1a = ja < len1 ? __int_as_float(e1a.y) : 0.f;
    float w1b = jb < len1 ? __int_as_float(e1b.y) : 0.f;
    p0 = fmaf(w0a, bf2f(x0a.x), p0); p1 = fmaf(w0a, bf2f(x0a.y), p1);
    p2 = fmaf(w0a, bf2f(x0a.z), p2); p3 = fmaf(w0a, bf2f(x0a.w), p3);
    p0 = fmaf(w0b, bf2f(x0b.x), p0); p1 = fmaf(w0b, bf2f(x0b.y), p1);
    p2 = fmaf(w0b, bf2f(x0b.z), p2); p3 = fmaf(w0b, bf2f(x0b.w), p3);
    r0a = fmaf(w1a, bf2f(x1a.x), r0a); r1a = fmaf(w1a, bf2f(x1a.y), r1a);
    r2a = fmaf(w1a, bf2f(x1a.z), r2a); r3a = fmaf(w1a, bf2f(x1a.w), r3a);
    r0a = fmaf(w1b, bf2f(x1b.x), r0a); r1a = fmaf(w1b, bf2f(x1b.y), r1a);
    r2a = fmaf(w1b, bf2f(x1b.z), r2a); r3a = fmaf(w1b, bf2f(x1b.w), r3a);
  }
  if (va) {
    const float* e0p = (row0 < split) ? (e0U + (size_t)row0 * 64)
                                      : (e0I + (size_t)(row0 - split) * 64);
    float4 ev = *(const float4*)(e0p + k * 4);
    ushort4 o;
    o.x = f2bf(p0 + ALPHA * ev.x);
    o.y = f2bf(p1 + ALPHA * ev.y);
    o.z = f2bf(p2 + ALPHA * ev.z);
    o.w = f2bf(p3 + ALPHA * ev.w);
    *(ushort4*)(dst + (size_t)row0 * 64 + k * 4) = o;
  }
  if (vb) {
    const float* e0p = (row1 < split) ? (e0U + (size_t)row1 * 64)
                                      : (e0I + (size_t)(row1 - split) * 64);
    float4 ev = *(const float4*)(e0p + k * 4);
    ushort4 o;
    o.x = f2bf(r0a + ALPHA * ev.x);
    o.y = f2bf(r1a + ALPHA * ev.y);
    o.z = f2bf(r2a + ALPHA * ev.z);
    o.w = f2bf(r3a + ALPHA * ev.w);
    *(ushort4*)(dst + (size_t)row1 * 64 + k * 4) = o;
  }
}

__global__ __launch_bounds__(256) void k_spmm(
    const unsigned short* __restrict__ src,
    const float* __restrict__ e0U, const float* __restrict__ e0I, int split,
    const int* __restrict__ perm, const int* __restrict__ rowptrS, const int* __restrict__ lenS,
    const int2* __restrict__ colval,
    unsigned short* __restrict__ dst, int n) {
  spmm_body((int)(blockIdx.x * 256 + threadIdx.x), src, e0U, e0I, split,
            perm, rowptrS, lenS, colval, dst, n);
}

// spmm layer-2 with fused accA: acc = E0_f32[sample] + 3*bf2f(ebA[sample])
__global__ __launch_bounds__(256) void k_spmm2_acc(
    const unsigned short* __restrict__ ebA,
    const float* __restrict__ e0U, const float* __restrict__ e0I, int split,
    const int* __restrict__ perm, const int* __restrict__ rowptrS, const int* __restrict__ lenS,
    const int2* __restrict__ colval,
    unsigned short* __restrict__ ebB, int n, int spmmBlocks,
    const int* __restrict__ users, const int* __restrict__ items, int B,
    const float* __restrict__ user_emb, const float* __restrict__ item_emb,
    float* __restrict__ accU, float* __restrict__ accI) {
  if ((int)blockIdx.x < spmmBlocks) {
    spmm_body((int)(blockIdx.x * 256 + threadIdx.x), ebA, e0U, e0I, split,
              perm, rowptrS, lenS, colval, ebB, n);
  } else {
    int t = ((int)blockIdx.x - spmmBlocks) * 256 + threadIdx.x;
    int total = B * 64;
    if (t < total) {
      int b = t >> 6, d = t & 63;
      size_t idx = (size_t)users[b] * 64 + d;
      accU[t] = user_emb[idx] + 3.f * bf2f(ebA[idx]);
    } else if (t < 2 * total) {
      int t2 = t - total;
      int b = t2 >> 6, d = t2 & 63;
      int r = items[b];
      accI[t2] = item_emb[(size_t)r * 64 + d] + 3.f * bf2f(ebA[(size_t)(split + r) * 64 + d]);
    }
  }
}

// ---------------- fused layer-3 mini-SpMM + 2*E2 term (8192 sampled rows) ----------------

__global__ __launch_bounds__(256) void k_mini3(
    const int* __restrict__ users, const int* __restrict__ items, int B, int split,
    const unsigned short* __restrict__ ebB,
    const float* __restrict__ e0U, const float* __restrict__ e0I,
    const int* __restrict__ rowptr, const int* __restrict__ cnt,
    const int2* __restrict__ colval,
    float* __restrict__ accU, float* __restrict__ accI) {
  int wave = (int)((blockIdx.x * blockDim.x + threadIdx.x) >> 6);
  int lane = threadIdx.x & 63;
  int sub = lane >> 4;
  int k   = lane & 15;
  int idx = wave * 4 + sub;
  bool valid = idx < 2 * B;
  int ic = valid ? idx : 0;
  int row;
  float* accp;
  if (ic < B) { row = users[ic];             accp = accU + (size_t)ic * 64; }
  else        { row = split + items[ic - B]; accp = accI + (size_t)(ic - B) * 64; }
  int start = rowptr[row];
  int len   = valid ? cnt[row] : 0;
  int maxlen = len;
  maxlen = max(maxlen, __shfl_xor(maxlen, 16));
  maxlen = max(maxlen, __shfl_xor(maxlen, 32));
  const int2* cv = colval + start;
  const unsigned short* srcK = ebB + (size_t)k * 4;
  int lenm1 = (len > 0) ? (len - 1) : 0;

  float a0 = 0.f, a1 = 0.f, a2 = 0.f, a3 = 0.f;
  for (int j = 0; j < maxlen; j += 4) {
#pragma unroll
    for (int u = 0; u < 4; u++) {
      int jj = j + u;
      int jc = (jj < len) ? jj : lenm1;
      int2 e = cv[jc];
      float v = (jj < len) ? __int_as_float(e.y) : 0.f;
      ushort4 x = *(const ushort4*)(srcK + (size_t)e.x * 64);
      a0 = fmaf(v, bf2f(x.x), a0);
      a1 = fmaf(v, bf2f(x.y), a1);
      a2 = fmaf(v, bf2f(x.z), a2);
      a3 = fmaf(v, bf2f(x.w), a3);
    }
  }
  if (valid) {
    const float* e0p = (row < split) ? (e0U + (size_t)row * 64)
                                     : (e0I + (size_t)(row - split) * 64);
    float4 ev = *(const float4*)(e0p + k * 4);
    ushort4 x2 = *(const ushort4*)(srcK + (size_t)row * 64);  // E2[row], fused 2x term
    float4 cur = *(const float4*)(accp + k * 4);
    cur.x += a0 + ALPHA * ev.x + 2.f * bf2f(x2.x);
    cur.y += a1 + ALPHA * ev.y + 2.f * bf2f(x2.y);
    cur.z += a2 + ALPHA * ev.z + 2.f * bf2f(x2.z);
    cur.w += a3 + ALPHA * ev.w + 2.f * bf2f(x2.w);
    *(float4*)(accp + k * 4) = cur;
  }
}

__global__ void k_dot(const float* __restrict__ accU, const float* __restrict__ accI, int B,
                      float* __restrict__ out) {
  int wave = (int)((blockIdx.x * blockDim.x + threadIdx.x) >> 6);
  int lane = threadIdx.x & 63;
  if (wave >= B) return;
  float p = accU[(size_t)wave * 64 + lane] * accI[(size_t)wave * 64 + lane];
  for (int d = 32; d > 0; d >>= 1) p += __shfl_xor(p, d);
  if (lane == 0) out[wave] = p * (1.f / 16.f);  // (1/4) layer mean x (1/4) weight norm
}

// ---------------- launch ----------------

extern "C" void kernel_launch(void* const* d_in, const int* in_sizes, int n_in,
                              void* d_out, int out_size, void* d_ws, size_t ws_size,
                              hipStream_t stream) {
  const int*   users     = (const int*)d_in[0];
  const int*   items     = (const int*)d_in[1];
  const int*   rows      = (const int*)d_in[2];
  const int*   cols      = (const int*)d_in[3];
  const float* vals      = (const float*)d_in[4];
  const float* user_emb  = (const float*)d_in[5];
  const float* item_emb  = (const float*)d_in[6];
  const float* user_emb0 = (const float*)d_in[7];
  const float* item_emb0 = (const float*)d_in[8];
  float* gamma = (float*)d_out;

  int B   = in_sizes[0];
  int nnz = in_sizes[2];
  int nU  = in_sizes[5] / 64;
  int nI  = in_sizes[6] / 64;
  int N   = nU + nI;
  int nb  = (N + RPB - 1) >> BSHIFT;   // 586 buckets

  char* base = (char*)d_ws;
  unsigned short* ebIn = (unsigned short*)base;          // N*64 bf16
  unsigned short* ebA  = ebIn + (size_t)N * 64;          // N*64 bf16 (layer-1 out)
  unsigned short* ebB  = ebA  + (size_t)N * 64;          // N*64 bf16 (layer-2 out)
  uint2* pPay = (uint2*)ebA;                             // overlay: dead before layer-1 spmm
  char* p = (char*)(ebB + (size_t)N * 64);
  int2* colval  = (int2*)p;           p += ((size_t)nnz + 8) * sizeof(int2);
  int*  rowptr  = (int*)p;            p += (size_t)N * sizeof(int);
  int*  cnt     = (int*)p;            p += (size_t)N * sizeof(int);
  int*  perm    = (int*)p;            p += (size_t)N * sizeof(int);
  int*  rowptrS = (int*)p;            p += (size_t)N * sizeof(int);
  int*  lenS    = (int*)p;            p += (size_t)N * sizeof(int);
  int*  bcnt    = (int*)p;            p += MAXB * sizeof(int);
  int*  degHist = (int*)p;            p += 256 * sizeof(int);
  int*  bptr    = (int*)p;            p += (MAXB + 1) * sizeof(int);
  int*  bcur    = (int*)p;            p += MAXB * sizeof(int);
  int*  degCur  = (int*)p;            p += 256 * sizeof(int);
  float* accU   = (float*)p;          p += (size_t)B * 64 * sizeof(float);
  float* accI   = (float*)p;          p += (size_t)B * 64 * sizeof(float);

  hipMemsetAsync(bcnt, 0, (MAXB + 256) * sizeof(int), stream);  // bcnt + degHist contiguous

  const int tpb = 256;
  int nTot = N * 64;
  int convBlocks = (nTot / 4 + tpb - 1) / tpb;
  k_conv_bucket<<<512 + convBlocks, tpb, 0, stream>>>(rows, nnz, bcnt,
                                                      user_emb, item_emb, nU * 64, nTot, ebIn);
  k_scan_buckets<<<1, 256, 0, stream>>>(bcnt, nb, bptr, bcur);
  k_partition<<<(nnz + CHUNK - 1) / CHUNK, tpb, 0, stream>>>(rows, cols, vals, nnz, bcur, pPay);
  k_build_csr<<<nb, tpb, 0, stream>>>(bptr, pPay, N, rowptr, cnt, colval, degHist);
  k_degscan<<<1, 256, 0, stream>>>(degHist, degCur, colval, nnz);
  k_permute<<<(N + 511) / 512, tpb, 0, stream>>>(rowptr, cnt, N, degCur, perm, rowptrS, lenS);

  // 32 rows per 256-thread block (4 waves x 4 quarters x 2 rows)
  int spmmBlocks = (N + 31) / 32;
  int accBlocks = (2 * B * 64 + tpb - 1) / tpb;

  // layer 1: src = ebIn, dst = ebA (pPay dead from here)
  k_spmm<<<spmmBlocks, tpb, 0, stream>>>(ebIn, user_emb0, item_emb0, nU,
                                         perm, rowptrS, lenS, colval, ebA, N);

  // layer 2 + fused accA (E0 + 3*E1 at sampled rows)
  k_spmm2_acc<<<spmmBlocks + accBlocks, tpb, 0, stream>>>(ebA, user_emb0, item_emb0, nU,
                                                          perm, rowptrS, lenS, colval, ebB, N,
                                                          spmmBlocks, users, items, B,
                                                          user_emb, item_emb, accU, accI);

  // layer 3 sampled rows + fused 2*E2 term
  int mBlocks = (2 * B + 15) / 16;
  k_mini3<<<mBlocks, tpb, 0, stream>>>(users, items, B, nU, ebB,
                                       user_emb0, item_emb0,
                                       rowptr, cnt, colval, accU, accI);

  k_dot<<<(B * 64 + tpb - 1) / tpb, tpb, 0, stream>>>(accU, accI, B, gamma);
}

// Round 4
// 626.514 us; speedup vs baseline: 1.1462x; 1.0552x over previous
//
#include <hip/hip_runtime.h>

#define ALPHA 0.5f
#define BSHIFT 11                // 2048 rows per bucket
#define RPB 2048
#define MAXB 256                 // >= nBuckets (147)
#define CHUNK 8192               // edges per partition block

// ---------------- bf16 helpers ----------------

__device__ __forceinline__ float bf2f(unsigned short u) {
  return __uint_as_float((unsigned)u << 16);
}
__device__ __forceinline__ unsigned short f2bf(float f) {
  unsigned u = __float_as_uint(f);
  u += 0x7fffu + ((u >> 16) & 1u);   // round-to-nearest-even
  return (unsigned short)(u >> 16);
}

// ---------------- fused: bucket counts (blocks 0..511) + f32->bf16 convert ----------------

__global__ __launch_bounds__(256) void k_conv_bucket(
    const int* __restrict__ rows, int nnz, int* __restrict__ bcnt,
    const float* __restrict__ uE, const float* __restrict__ iE,
    int nU64, int nTot, unsigned short* __restrict__ out) {
  __shared__ int lcnt[MAXB];
  int t = threadIdx.x;
  if (blockIdx.x < 512) {
    if (t < MAXB) lcnt[t] = 0;
    __syncthreads();
    int stride = 512 * 256;
    for (int e = blockIdx.x * 256 + t; e < nnz; e += stride)
      atomicAdd(&lcnt[rows[e] >> BSHIFT], 1);
    __syncthreads();
    if (t < MAXB) {
      int c = lcnt[t];
      if (c) atomicAdd(&bcnt[t], c);
    }
  } else {
    int i = ((int)(blockIdx.x - 512) * 256 + t) * 4;
    if (i >= nTot) return;
    const float* src = (i < nU64) ? (uE + i) : (iE + (i - nU64));
    float4 v = *(const float4*)src;
    ushort4 o;
    o.x = f2bf(v.x); o.y = f2bf(v.y); o.z = f2bf(v.z); o.w = f2bf(v.w);
    *(ushort4*)(out + i) = o;
  }
}

// ---------------- scan bucket counts -> bptr, bcur ----------------

__global__ void k_scan_buckets(const int* __restrict__ bcnt, int nb,
                               int* __restrict__ bptr, int* __restrict__ bcur) {
  __shared__ int s[256];
  int t = threadIdx.x;
  int v = (t < nb) ? bcnt[t] : 0;
  s[t] = v; __syncthreads();
  for (int d = 1; d < 256; d <<= 1) {
    int x = (t >= d) ? s[t - d] : 0;
    __syncthreads();
    s[t] += x;
    __syncthreads();
  }
  if (t < nb) {
    int excl = s[t] - v;
    bptr[t] = excl;
    bcur[t] = excl;
  }
  if (t == 0) bptr[nb] = s[255];   // total
}

// ---------------- partition edges into buckets (packed 8B payload) ----------------
// 147 coarse buckets: per-(chunk,bucket) run ~56 edges = 448B -> full-line writes.
// (BSHIFT=9 variant measured: 132us, WRITE 136MB from 112B runs. Reverted.)

__global__ __launch_bounds__(256) void k_partition(
    const int* __restrict__ rows, const int* __restrict__ cols, const float* __restrict__ vals,
    int nnz, int* __restrict__ bcur, uint2* __restrict__ pPay) {
  __shared__ int lcnt[MAXB];
  __shared__ int lbase[MAXB];
  int t = threadIdx.x;
  if (t < MAXB) lcnt[t] = 0;
  __syncthreads();
  int base = blockIdx.x * CHUNK;
  int end = nnz < base + CHUNK ? nnz : base + CHUNK;
  for (int e = base + t; e < end; e += 256)
    atomicAdd(&lcnt[rows[e] >> BSHIFT], 1);
  __syncthreads();
  if (t < MAXB) {
    int c = lcnt[t];
    lbase[t] = c ? atomicAdd(&bcur[t], c) : 0;
    lcnt[t] = 0;
  }
  __syncthreads();
  for (int e = base + t; e < end; e += 256) {
    int r = rows[e];
    int b = r >> BSHIFT;
    int p = lbase[b] + atomicAdd(&lcnt[b], 1);
    uint2 pay;
    pay.x = ((unsigned)(r & (RPB - 1)) << 20) | (unsigned)cols[e];
    pay.y = __float_as_uint(vals[e]);
    pPay[p] = pay;
  }
}

// ---------------- per-bucket CSR build + degree histogram ----------------
// 1024 threads (16 waves): 4x per-bucket parallelism vs r0's 256 threads,
// same 147 blocks / same traffic; each latency-bound pass 133 -> 33 iters.

__global__ __launch_bounds__(1024) void k_build_csr(
    const int* __restrict__ bptr, const uint2* __restrict__ pPay, int N,
    int* __restrict__ rowptr, int* __restrict__ cnt, int2* __restrict__ colval,
    int* __restrict__ degHist) {
  __shared__ int lcnt[RPB];        // 8 KB: counts -> cursors
  __shared__ int scanbuf[1024];
  __shared__ int ldeg[256];
  int t = threadIdx.x;
  int b = blockIdx.x;
  int r0 = b << BSHIFT;
  int rCount = N - r0; if (rCount > RPB) rCount = RPB;
  int eBeg = bptr[b], eEnd = bptr[b + 1];

  for (int r = t; r < RPB; r += 1024) lcnt[r] = 0;
  if (t < 256) ldeg[t] = 0;
  __syncthreads();
  for (int e = eBeg + t; e < eEnd; e += 1024)
    atomicAdd(&lcnt[pPay[e].x >> 20], 1);
  __syncthreads();
  for (int r = t; r < rCount; r += 1024) {
    int c = lcnt[r];
    cnt[r0 + r] = c;
    atomicAdd(&ldeg[c < 255 ? c : 255], 1);
  }
  int v2[2]; int s = 0;
#pragma unroll
  for (int k = 0; k < 2; k++) {
    int x = lcnt[2 * t + k];
    v2[k] = s; s += x;
  }
  scanbuf[t] = s; __syncthreads();
  for (int d = 1; d < 1024; d <<= 1) {
    int x = (t >= d) ? scanbuf[t - d] : 0;
    __syncthreads();
    scanbuf[t] += x;
    __syncthreads();
  }
  int blockExcl = scanbuf[t] - s;
#pragma unroll
  for (int k = 0; k < 2; k++) lcnt[2 * t + k] = blockExcl + v2[k];
  __syncthreads();
  if (t < 256 && ldeg[t]) atomicAdd(&degHist[t], ldeg[t]);
  for (int r = t; r < rCount; r += 1024) rowptr[r0 + r] = eBeg + lcnt[r];
  __syncthreads();
  for (int e = eBeg + t; e < eEnd; e += 1024) {
    uint2 pay = pPay[e];
    int r = (int)(pay.x >> 20);
    int p = eBeg + atomicAdd(&lcnt[r], 1);
    int2 cv; cv.x = (int)(pay.x & 0xFFFFFu); cv.y = (int)pay.y;
    colval[p] = cv;
  }
}

// ---------------- degree-bin scan (1 block) + colval pad init ----------------

__global__ void k_degscan(const int* __restrict__ degHist, int* __restrict__ degCur,
                          int2* __restrict__ colval, int nnz) {
  __shared__ int s[256];
  int t = threadIdx.x;
  int v = degHist[t];
  s[t] = v; __syncthreads();
  for (int d = 1; d < 256; d <<= 1) {
    int x = (t >= d) ? s[t - d] : 0;
    __syncthreads();
    s[t] += x;
    __syncthreads();
  }
  degCur[t] = s[t] - v;   // exclusive
  if (t < 8) { int2 z; z.x = 0; z.y = 0; colval[nnz + t] = z; }
}

// ---------------- permute rows into degree-sorted order ----------------

__global__ __launch_bounds__(256) void k_permute(
    const int* __restrict__ rowptr, const int* __restrict__ cnt, int N,
    int* __restrict__ degCur,
    int* __restrict__ perm, int* __restrict__ rowptrS, int* __restrict__ lenS) {
  __shared__ int lcnt[256];
  __shared__ int lbase[256];
  int t = threadIdx.x;
  lcnt[t] = 0;
  __syncthreads();
  int base = blockIdx.x * 1024;
  int end = N < base + 1024 ? N : base + 1024;
  for (int r = base + t; r < end; r += 256) {
    int c = cnt[r];
    atomicAdd(&lcnt[c < 255 ? c : 255], 1);
  }
  __syncthreads();
  {
    int c = lcnt[t];
    lbase[t] = c ? atomicAdd(&degCur[t], c) : 0;
    lcnt[t] = 0;
  }
  __syncthreads();
  for (int r = base + t; r < end; r += 256) {
    int c = cnt[r];
    int bin = c < 255 ? c : 255;
    int pos = lbase[bin] + atomicAdd(&lcnt[bin], 1);
    perm[pos] = r;
    rowptrS[pos] = rowptr[r];
    lenS[pos] = c;
  }
}

// ---------------- SpMM core: quarter-wave owns 2 degree-adjacent rows ----------------
// (round-0 proven body; pipeline/unroll variants measured slower in r1/r2)

__device__ __forceinline__ void spmm_body(
    int gtid,
    const unsigned short* __restrict__ src,
    const float* __restrict__ e0U, const float* __restrict__ e0I, int split,
    const int* __restrict__ perm, const int* __restrict__ rowptrS, const int* __restrict__ lenS,
    const int2* __restrict__ colval,
    unsigned short* __restrict__ dst, int n) {
  int wave = gtid >> 6;
  int lane = gtid & 63;
  int sub = lane >> 4;
  int k   = lane & 15;
  int q = wave * 4 + sub;
  int s0 = 2 * q, s1 = 2 * q + 1;
  bool va = s0 < n, vb = s1 < n;
  int i0 = va ? s0 : 0, i1 = vb ? s1 : 0;
  int row0 = perm[i0], row1 = perm[i1];
  int st0 = rowptrS[i0], st1 = rowptrS[i1];
  int len0 = va ? lenS[i0] : 0, len1 = vb ? lenS[i1] : 0;
  const int2* cv0 = colval + st0;
  const int2* cv1 = colval + st1;
  const unsigned short* srcK = src + (size_t)k * 4;
  int l0m = len0 > 0 ? len0 - 1 : 0;
  int l1m = len1 > 0 ? len1 - 1 : 0;
  int mx = max(len0, len1);

  float p0 = 0.f, p1 = 0.f, p2 = 0.f, p3 = 0.f;   // row0
  float r0a = 0.f, r1a = 0.f, r2a = 0.f, r3a = 0.f; // row1
  for (int j = 0; j < mx; j += 2) {
    int ja = j, jb = j + 1;
    int j0a = ja < l0m ? ja : l0m, j0b = jb < l0m ? jb : l0m;
    int j1a = ja < l1m ? ja : l1m, j1b = jb < l1m ? jb : l1m;
    int2 e0a = cv0[j0a];
    int2 e0b = cv0[j0b];
    int2 e1a = cv1[j1a];
    int2 e1b = cv1[j1b];
    ushort4 x0a = *(const ushort4*)(srcK + (size_t)e0a.x * 64);
    ushort4 x0b = *(const ushort4*)(srcK + (size_t)e0b.x * 64);
    ushort4 x1a = *(const ushort4*)(srcK + (size_t)e1a.x * 64);
    ushort4 x1b = *(const ushort4*)(srcK + (size_t)e1b.x * 64);
    float w0a = ja < len0 ? __int_as_float(e0a.y) : 0.f;
    float w0b = jb < len0 ? __int_as_float(e0b.y) : 0.f;
    float w1a = ja < len1 ? __int_as_float(e1a.y) : 0.f;
    float w1b = jb < len1 ? __int_as_float(e1b.y) : 0.f;
    p0 = fmaf(w0a, bf2f(x0a.x), p0); p1 = fmaf(w0a, bf2f(x0a.y), p1);
    p2 = fmaf(w0a, bf2f(x0a.z), p2); p3 = fmaf(w0a, bf2f(x0a.w), p3);
    p0 = fmaf(w0b, bf2f(x0b.x), p0); p1 = fmaf(w0b, bf2f(x0b.y), p1);
    p2 = fmaf(w0b, bf2f(x0b.z), p2); p3 = fmaf(w0b, bf2f(x0b.w), p3);
    r0a = fmaf(w1a, bf2f(x1a.x), r0a); r1a = fmaf(w1a, bf2f(x1a.y), r1a);
    r2a = fmaf(w1a, bf2f(x1a.z), r2a); r3a = fmaf(w1a, bf2f(x1a.w), r3a);
    r0a = fmaf(w1b, bf2f(x1b.x), r0a); r1a = fmaf(w1b, bf2f(x1b.y), r1a);
    r2a = fmaf(w1b, bf2f(x1b.z), r2a); r3a = fmaf(w1b, bf2f(x1b.w), r3a);
  }
  if (va) {
    const float* e0p = (row0 < split) ? (e0U + (size_t)row0 * 64)
                                      : (e0I + (size_t)(row0 - split) * 64);
    float4 ev = *(const float4*)(e0p + k * 4);
    ushort4 o;
    o.x = f2bf(p0 + ALPHA * ev.x);
    o.y = f2bf(p1 + ALPHA * ev.y);
    o.z = f2bf(p2 + ALPHA * ev.z);
    o.w = f2bf(p3 + ALPHA * ev.w);
    *(ushort4*)(dst + (size_t)row0 * 64 + k * 4) = o;
  }
  if (vb) {
    const float* e0p = (row1 < split) ? (e0U + (size_t)row1 * 64)
                                      : (e0I + (size_t)(row1 - split) * 64);
    float4 ev = *(const float4*)(e0p + k * 4);
    ushort4 o;
    o.x = f2bf(r0a + ALPHA * ev.x);
    o.y = f2bf(r1a + ALPHA * ev.y);
    o.z = f2bf(r2a + ALPHA * ev.z);
    o.w = f2bf(r3a + ALPHA * ev.w);
    *(ushort4*)(dst + (size_t)row1 * 64 + k * 4) = o;
  }
}

__global__ __launch_bounds__(256) void k_spmm(
    const unsigned short* __restrict__ src,
    const float* __restrict__ e0U, const float* __restrict__ e0I, int split,
    const int* __restrict__ perm, const int* __restrict__ rowptrS, const int* __restrict__ lenS,
    const int2* __restrict__ colval,
    unsigned short* __restrict__ dst, int n) {
  spmm_body((int)(blockIdx.x * 256 + threadIdx.x), src, e0U, e0I, split,
            perm, rowptrS, lenS, colval, dst, n);
}

// spmm layer-2 with fused accA: acc = E0_f32[sample] + 3*bf2f(ebA[sample])
__global__ __launch_bounds__(256) void k_spmm2_acc(
    const unsigned short* __restrict__ ebA,
    const float* __restrict__ e0U, const float* __restrict__ e0I, int split,
    const int* __restrict__ perm, const int* __restrict__ rowptrS, const int* __restrict__ lenS,
    const int2* __restrict__ colval,
    unsigned short* __restrict__ ebB, int n, int spmmBlocks,
    const int* __restrict__ users, const int* __restrict__ items, int B,
    const float* __restrict__ user_emb, const float* __restrict__ item_emb,
    float* __restrict__ accU, float* __restrict__ accI) {
  if ((int)blockIdx.x < spmmBlocks) {
    spmm_body((int)(blockIdx.x * 256 + threadIdx.x), ebA, e0U, e0I, split,
              perm, rowptrS, lenS, colval, ebB, n);
  } else {
    int t = ((int)blockIdx.x - spmmBlocks) * 256 + threadIdx.x;
    int total = B * 64;
    if (t < total) {
      int b = t >> 6, d = t & 63;
      size_t idx = (size_t)users[b] * 64 + d;
      accU[t] = user_emb[idx] + 3.f * bf2f(ebA[idx]);
    } else if (t < 2 * total) {
      int t2 = t - total;
      int b = t2 >> 6, d = t2 & 63;
      int r = items[b];
      accI[t2] = item_emb[(size_t)r * 64 + d] + 3.f * bf2f(ebA[(size_t)(split + r) * 64 + d]);
    }
  }
}

// ---------------- fused layer-3 mini-SpMM + 2*E2 term (8192 sampled rows) ----------------

__global__ __launch_bounds__(256) void k_mini3(
    const int* __restrict__ users, const int* __restrict__ items, int B, int split,
    const unsigned short* __restrict__ ebB,
    const float* __restrict__ e0U, const float* __restrict__ e0I,
    const int* __restrict__ rowptr, const int* __restrict__ cnt,
    const int2* __restrict__ colval,
    float* __restrict__ accU, float* __restrict__ accI) {
  int wave = (int)((blockIdx.x * blockDim.x + threadIdx.x) >> 6);
  int lane = threadIdx.x & 63;
  int sub = lane >> 4;
  int k   = lane & 15;
  int idx = wave * 4 + sub;
  bool valid = idx < 2 * B;
  int ic = valid ? idx : 0;
  int row;
  float* accp;
  if (ic < B) { row = users[ic];             accp = accU + (size_t)ic * 64; }
  else        { row = split + items[ic - B]; accp = accI + (size_t)(ic - B) * 64; }
  int start = rowptr[row];
  int len   = valid ? cnt[row] : 0;
  int maxlen = len;
  maxlen = max(maxlen, __shfl_xor(maxlen, 16));
  maxlen = max(maxlen, __shfl_xor(maxlen, 32));
  const int2* cv = colval + start;
  const unsigned short* srcK = ebB + (size_t)k * 4;
  int lenm1 = (len > 0) ? (len - 1) : 0;

  float a0 = 0.f, a1 = 0.f, a2 = 0.f, a3 = 0.f;
  for (int j = 0; j < maxlen; j += 4) {
#pragma unroll
    for (int u = 0; u < 4; u++) {
      int jj = j + u;
      int jc = (jj < len) ? jj : lenm1;
      int2 e = cv[jc];
      float v = (jj < len) ? __int_as_float(e.y) : 0.f;
      ushort4 x = *(const ushort4*)(srcK + (size_t)e.x * 64);
      a0 = fmaf(v, bf2f(x.x), a0);
      a1 = fmaf(v, bf2f(x.y), a1);
      a2 = fmaf(v, bf2f(x.z), a2);
      a3 = fmaf(v, bf2f(x.w), a3);
    }
  }
  if (valid) {
    const float* e0p = (row < split) ? (e0U + (size_t)row * 64)
                                     : (e0I + (size_t)(row - split) * 64);
    float4 ev = *(const float4*)(e0p + k * 4);
    ushort4 x2 = *(const ushort4*)(srcK + (size_t)row * 64);  // E2[row], fused 2x term
    float4 cur = *(const float4*)(accp + k * 4);
    cur.x += a0 + ALPHA * ev.x + 2.f * bf2f(x2.x);
    cur.y += a1 + ALPHA * ev.y + 2.f * bf2f(x2.y);
    cur.z += a2 + ALPHA * ev.z + 2.f * bf2f(x2.z);
    cur.w += a3 + ALPHA * ev.w + 2.f * bf2f(x2.w);
    *(float4*)(accp + k * 4) = cur;
  }
}

__global__ void k_dot(const float* __restrict__ accU, const float* __restrict__ accI, int B,
                      float* __restrict__ out) {
  int wave = (int)((blockIdx.x * blockDim.x + threadIdx.x) >> 6);
  int lane = threadIdx.x & 63;
  if (wave >= B) return;
  float p = accU[(size_t)wave * 64 + lane] * accI[(size_t)wave * 64 + lane];
  for (int d = 32; d > 0; d >>= 1) p += __shfl_xor(p, d);
  if (lane == 0) out[wave] = p * (1.f / 16.f);  // (1/4) layer mean x (1/4) weight norm
}

// ---------------- launch ----------------

extern "C" void kernel_launch(void* const* d_in, const int* in_sizes, int n_in,
                              void* d_out, int out_size, void* d_ws, size_t ws_size,
                              hipStream_t stream) {
  const int*   users     = (const int*)d_in[0];
  const int*   items     = (const int*)d_in[1];
  const int*   rows      = (const int*)d_in[2];
  const int*   cols      = (const int*)d_in[3];
  const float* vals      = (const float*)d_in[4];
  const float* user_emb  = (const float*)d_in[5];
  const float* item_emb  = (const float*)d_in[6];
  const float* user_emb0 = (const float*)d_in[7];
  const float* item_emb0 = (const float*)d_in[8];
  float* gamma = (float*)d_out;

  int B   = in_sizes[0];
  int nnz = in_sizes[2];
  int nU  = in_sizes[5] / 64;
  int nI  = in_sizes[6] / 64;
  int N   = nU + nI;
  int nb  = (N + RPB - 1) >> BSHIFT;   // 147 buckets

  char* base = (char*)d_ws;
  unsigned short* ebIn = (unsigned short*)base;          // N*64 bf16
  unsigned short* ebA  = ebIn + (size_t)N * 64;          // N*64 bf16 (layer-1 out)
  unsigned short* ebB  = ebA  + (size_t)N * 64;          // N*64 bf16 (layer-2 out)
  uint2* pPay = (uint2*)ebA;                             // overlay: dead before layer-1 spmm
  char* p = (char*)(ebB + (size_t)N * 64);
  int2* colval  = (int2*)p;           p += ((size_t)nnz + 8) * sizeof(int2);
  int*  rowptr  = (int*)p;            p += (size_t)N * sizeof(int);
  int*  cnt     = (int*)p;            p += (size_t)N * sizeof(int);
  int*  perm    = (int*)p;            p += (size_t)N * sizeof(int);
  int*  rowptrS = (int*)p;            p += (size_t)N * sizeof(int);
  int*  lenS    = (int*)p;            p += (size_t)N * sizeof(int);
  int*  bcnt    = (int*)p;            p += MAXB * sizeof(int);
  int*  degHist = (int*)p;            p += 256 * sizeof(int);
  int*  bptr    = (int*)p;            p += (MAXB + 1) * sizeof(int);
  int*  bcur    = (int*)p;            p += MAXB * sizeof(int);
  int*  degCur  = (int*)p;            p += 256 * sizeof(int);
  float* accU   = (float*)p;          p += (size_t)B * 64 * sizeof(float);
  float* accI   = (float*)p;          p += (size_t)B * 64 * sizeof(float);

  hipMemsetAsync(bcnt, 0, (MAXB + 256) * sizeof(int), stream);  // bcnt + degHist contiguous

  const int tpb = 256;
  int nTot = N * 64;
  int convBlocks = (nTot / 4 + tpb - 1) / tpb;
  k_conv_bucket<<<512 + convBlocks, tpb, 0, stream>>>(rows, nnz, bcnt,
                                                      user_emb, item_emb, nU * 64, nTot, ebIn);
  k_scan_buckets<<<1, 256, 0, stream>>>(bcnt, nb, bptr, bcur);
  k_partition<<<(nnz + CHUNK - 1) / CHUNK, tpb, 0, stream>>>(rows, cols, vals, nnz, bcur, pPay);
  k_build_csr<<<nb, 1024, 0, stream>>>(bptr, pPay, N, rowptr, cnt, colval, degHist);
  k_degscan<<<1, 256, 0, stream>>>(degHist, degCur, colval, nnz);
  k_permute<<<(N + 1023) / 1024, tpb, 0, stream>>>(rowptr, cnt, N, degCur, perm, rowptrS, lenS);

  // 32 rows per 256-thread block (4 waves x 4 quarters x 2 rows)
  int spmmBlocks = (N + 31) / 32;
  int accBlocks = (2 * B * 64 + tpb - 1) / tpb;

  // layer 1: src = ebIn, dst = ebA (pPay dead from here)
  k_spmm<<<spmmBlocks, tpb, 0, stream>>>(ebIn, user_emb0, item_emb0, nU,
                                         perm, rowptrS, lenS, colval, ebA, N);

  // layer 2 + fused accA (E0 + 3*E1 at sampled rows)
  k_spmm2_acc<<<spmmBlocks + accBlocks, tpb, 0, stream>>>(ebA, user_emb0, item_emb0, nU,
                                                          perm, rowptrS, lenS, colval, ebB, N,
                                                          spmmBlocks, users, items, B,
                                                          user_emb, item_emb, accU, accI);

  // layer 3 sampled rows + fused 2*E2 term
  int mBlocks = (2 * B + 15) / 16;
  k_mini3<<<mBlocks, tpb, 0, stream>>>(users, items, B, nU, ebB,
                                       user_emb0, item_emb0,
                                       rowptr, cnt, colval, accU, accI);

  k_dot<<<(B * 64 + tpb - 1) / tpb, tpb, 0, stream>>>(accU, accI, B, gamma);
}

// Round 5
// 615.561 us; speedup vs baseline: 1.1666x; 1.0178x over previous
//
#include <hip/hip_runtime.h>

#define ALPHA 0.5f
#define BSHIFT 11                // 2048 rows per bucket
#define RPB 2048
#define MAXB 256                 // >= nBuckets (147)
#define PCHUNK 16384             // edges per partition block (1024 threads)

// ---------------- bf16 helpers ----------------

__device__ __forceinline__ float bf2f(unsigned short u) {
  return __uint_as_float((unsigned)u << 16);
}
__device__ __forceinline__ unsigned short f2bf(float f) {
  unsigned u = __float_as_uint(f);
  u += 0x7fffu + ((u >> 16) & 1u);   // round-to-nearest-even
  return (unsigned short)(u >> 16);
}

// ---------------- bucket counts only (rows -> bcnt) ----------------

__global__ __launch_bounds__(256) void k_count(
    const int* __restrict__ rows, int nnz, int* __restrict__ bcnt) {
  __shared__ int lcnt[MAXB];
  int t = threadIdx.x;
  if (t < MAXB) lcnt[t] = 0;
  __syncthreads();
  int stride = 512 * 256;
  for (int e = blockIdx.x * 256 + t; e < nnz; e += stride)
    atomicAdd(&lcnt[rows[e] >> BSHIFT], 1);
  __syncthreads();
  if (t < MAXB) {
    int c = lcnt[t];
    if (c) atomicAdd(&bcnt[t], c);
  }
}

// ---------------- scan bucket counts -> bptr, bcur ----------------

__global__ void k_scan_buckets(const int* __restrict__ bcnt, int nb,
                               int* __restrict__ bptr, int* __restrict__ bcur) {
  __shared__ int s[256];
  int t = threadIdx.x;
  int v = (t < nb) ? bcnt[t] : 0;
  s[t] = v; __syncthreads();
  for (int d = 1; d < 256; d <<= 1) {
    int x = (t >= d) ? s[t - d] : 0;
    __syncthreads();
    s[t] += x;
    __syncthreads();
  }
  if (t < nb) {
    int excl = s[t] - v;
    bptr[t] = excl;
    bcur[t] = excl;
  }
  if (t == 0) bptr[nb] = s[255];   // total
}

// ---------------- fused: partition (blocks < PB) + f32->bf16 convert ----------------
// Partition blocks are scatter/latency-bound at low VALU use; convert blocks
// backfill idle issue slots on the same launch (independent until spmm1).
// 1024 threads, CHUNK=16384: per-(chunk,bucket) run ~112 edges = 896B.

__global__ __launch_bounds__(1024) void k_part_conv(
    const int* __restrict__ rows, const int* __restrict__ cols, const float* __restrict__ vals,
    int nnz, int* __restrict__ bcur, uint2* __restrict__ pPay, int PB,
    const float* __restrict__ uE, const float* __restrict__ iE,
    int nU64, int nTot, unsigned short* __restrict__ out) {
  __shared__ int lcnt[MAXB];
  __shared__ int lbase[MAXB];
  int t = threadIdx.x;
  if ((int)blockIdx.x < PB) {
    if (t < MAXB) lcnt[t] = 0;
    __syncthreads();
    int base = blockIdx.x * PCHUNK;
    int end = nnz < base + PCHUNK ? nnz : base + PCHUNK;
    for (int e = base + t; e < end; e += 1024)
      atomicAdd(&lcnt[rows[e] >> BSHIFT], 1);
    __syncthreads();
    if (t < MAXB) {
      int c = lcnt[t];
      lbase[t] = c ? atomicAdd(&bcur[t], c) : 0;
      lcnt[t] = 0;
    }
    __syncthreads();
    for (int e = base + t; e < end; e += 1024) {
      int r = rows[e];
      int b = r >> BSHIFT;
      int p = lbase[b] + atomicAdd(&lcnt[b], 1);
      uint2 pay;
      pay.x = ((unsigned)(r & (RPB - 1)) << 20) | (unsigned)cols[e];
      pay.y = __float_as_uint(vals[e]);
      pPay[p] = pay;
    }
  } else {
    int i = (((int)blockIdx.x - PB) * 1024 + t) * 4;
    if (i >= nTot) return;
    const float* src = (i < nU64) ? (uE + i) : (iE + (i - nU64));
    float4 v = *(const float4*)src;
    ushort4 o;
    o.x = f2bf(v.x); o.y = f2bf(v.y); o.z = f2bf(v.z); o.w = f2bf(v.w);
    *(ushort4*)(out + i) = o;
  }
}

// ---------------- per-bucket CSR build + degree histogram ----------------
// 1024 threads (16 waves): measured win in r4 (total 661 -> 626).

__global__ __launch_bounds__(1024) void k_build_csr(
    const int* __restrict__ bptr, const uint2* __restrict__ pPay, int N,
    int* __restrict__ rowptr, int* __restrict__ cnt, int2* __restrict__ colval,
    int* __restrict__ degHist) {
  __shared__ int lcnt[RPB];        // 8 KB: counts -> cursors
  __shared__ int scanbuf[1024];
  __shared__ int ldeg[256];
  int t = threadIdx.x;
  int b = blockIdx.x;
  int r0 = b << BSHIFT;
  int rCount = N - r0; if (rCount > RPB) rCount = RPB;
  int eBeg = bptr[b], eEnd = bptr[b + 1];

  for (int r = t; r < RPB; r += 1024) lcnt[r] = 0;
  if (t < 256) ldeg[t] = 0;
  __syncthreads();
  for (int e = eBeg + t; e < eEnd; e += 1024)
    atomicAdd(&lcnt[pPay[e].x >> 20], 1);
  __syncthreads();
  for (int r = t; r < rCount; r += 1024) {
    int c = lcnt[r];
    cnt[r0 + r] = c;
    atomicAdd(&ldeg[c < 255 ? c : 255], 1);
  }
  int v2[2]; int s = 0;
#pragma unroll
  for (int k = 0; k < 2; k++) {
    int x = lcnt[2 * t + k];
    v2[k] = s; s += x;
  }
  scanbuf[t] = s; __syncthreads();
  for (int d = 1; d < 1024; d <<= 1) {
    int x = (t >= d) ? scanbuf[t - d] : 0;
    __syncthreads();
    scanbuf[t] += x;
    __syncthreads();
  }
  int blockExcl = scanbuf[t] - s;
#pragma unroll
  for (int k = 0; k < 2; k++) lcnt[2 * t + k] = blockExcl + v2[k];
  __syncthreads();
  if (t < 256 && ldeg[t]) atomicAdd(&degHist[t], ldeg[t]);
  for (int r = t; r < rCount; r += 1024) rowptr[r0 + r] = eBeg + lcnt[r];
  __syncthreads();
  for (int e = eBeg + t; e < eEnd; e += 1024) {
    uint2 pay = pPay[e];
    int r = (int)(pay.x >> 20);
    int p = eBeg + atomicAdd(&lcnt[r], 1);
    int2 cv; cv.x = (int)(pay.x & 0xFFFFFu); cv.y = (int)pay.y;
    colval[p] = cv;
  }
}

// ---------------- degree-bin scan (1 block) + colval pad init ----------------

__global__ void k_degscan(const int* __restrict__ degHist, int* __restrict__ degCur,
                          int2* __restrict__ colval, int nnz) {
  __shared__ int s[256];
  int t = threadIdx.x;
  int v = degHist[t];
  s[t] = v; __syncthreads();
  for (int d = 1; d < 256; d <<= 1) {
    int x = (t >= d) ? s[t - d] : 0;
    __syncthreads();
    s[t] += x;
    __syncthreads();
  }
  degCur[t] = s[t] - v;   // exclusive
  if (t < 8) { int2 z; z.x = 0; z.y = 0; colval[nnz + t] = z; }
}

// ---------------- permute rows into degree-sorted order ----------------

__global__ __launch_bounds__(256) void k_permute(
    const int* __restrict__ rowptr, const int* __restrict__ cnt, int N,
    int* __restrict__ degCur,
    int* __restrict__ perm, int* __restrict__ rowptrS, int* __restrict__ lenS) {
  __shared__ int lcnt[256];
  __shared__ int lbase[256];
  int t = threadIdx.x;
  lcnt[t] = 0;
  __syncthreads();
  int base = blockIdx.x * 1024;
  int end = N < base + 1024 ? N : base + 1024;
  for (int r = base + t; r < end; r += 256) {
    int c = cnt[r];
    atomicAdd(&lcnt[c < 255 ? c : 255], 1);
  }
  __syncthreads();
  {
    int c = lcnt[t];
    lbase[t] = c ? atomicAdd(&degCur[t], c) : 0;
    lcnt[t] = 0;
  }
  __syncthreads();
  for (int r = base + t; r < end; r += 256) {
    int c = cnt[r];
    int bin = c < 255 ? c : 255;
    int pos = lbase[bin] + atomicAdd(&lcnt[bin], 1);
    perm[pos] = r;
    rowptrS[pos] = rowptr[r];
    lenS[pos] = c;
  }
}

// ---------------- SpMM core: quarter-wave owns 2 degree-adjacent rows ----------------
// (round-0 proven body; pipeline/unroll variants measured slower in r1/r2)

__device__ __forceinline__ void spmm_body(
    int gtid,
    const unsigned short* __restrict__ src,
    const float* __restrict__ e0U, const float* __restrict__ e0I, int split,
    const int* __restrict__ perm, const int* __restrict__ rowptrS, const int* __restrict__ lenS,
    const int2* __restrict__ colval,
    unsigned short* __restrict__ dst, int n) {
  int wave = gtid >> 6;
  int lane = gtid & 63;
  int sub = lane >> 4;
  int k   = lane & 15;
  int q = wave * 4 + sub;
  int s0 = 2 * q, s1 = 2 * q + 1;
  bool va = s0 < n, vb = s1 < n;
  int i0 = va ? s0 : 0, i1 = vb ? s1 : 0;
  int row0 = perm[i0], row1 = perm[i1];
  int st0 = rowptrS[i0], st1 = rowptrS[i1];
  int len0 = va ? lenS[i0] : 0, len1 = vb ? lenS[i1] : 0;
  const int2* cv0 = colval + st0;
  const int2* cv1 = colval + st1;
  const unsigned short* srcK = src + (size_t)k * 4;
  int l0m = len0 > 0 ? len0 - 1 : 0;
  int l1m = len1 > 0 ? len1 - 1 : 0;
  int mx = max(len0, len1);

  float p0 = 0.f, p1 = 0.f, p2 = 0.f, p3 = 0.f;   // row0
  float r0a = 0.f, r1a = 0.f, r2a = 0.f, r3a = 0.f; // row1
  for (int j = 0; j < mx; j += 2) {
    int ja = j, jb = j + 1;
    int j0a = ja < l0m ? ja : l0m, j0b = jb < l0m ? jb : l0m;
    int j1a = ja < l1m ? ja : l1m, j1b = jb < l1m ? jb : l1m;
    int2 e0a = cv0[j0a];
    int2 e0b = cv0[j0b];
    int2 e1a = cv1[j1a];
    int2 e1b = cv1[j1b];
    ushort4 x0a = *(const ushort4*)(srcK + (size_t)e0a.x * 64);
    ushort4 x0b = *(const ushort4*)(srcK + (size_t)e0b.x * 64);
    ushort4 x1a = *(const ushort4*)(srcK + (size_t)e1a.x * 64);
    ushort4 x1b = *(const ushort4*)(srcK + (size_t)e1b.x * 64);
    float w0a = ja < len0 ? __int_as_float(e0a.y) : 0.f;
    float w0b = jb < len0 ? __int_as_float(e0b.y) : 0.f;
    float w1a = ja < len1 ? __int_as_float(e1a.y) : 0.f;
    float w1b = jb < len1 ? __int_as_float(e1b.y) : 0.f;
    p0 = fmaf(w0a, bf2f(x0a.x), p0); p1 = fmaf(w0a, bf2f(x0a.y), p1);
    p2 = fmaf(w0a, bf2f(x0a.z), p2); p3 = fmaf(w0a, bf2f(x0a.w), p3);
    p0 = fmaf(w0b, bf2f(x0b.x), p0); p1 = fmaf(w0b, bf2f(x0b.y), p1);
    p2 = fmaf(w0b, bf2f(x0b.z), p2); p3 = fmaf(w0b, bf2f(x0b.w), p3);
    r0a = fmaf(w1a, bf2f(x1a.x), r0a); r1a = fmaf(w1a, bf2f(x1a.y), r1a);
    r2a = fmaf(w1a, bf2f(x1a.z), r2a); r3a = fmaf(w1a, bf2f(x1a.w), r3a);
    r0a = fmaf(w1b, bf2f(x1b.x), r0a); r1a = fmaf(w1b, bf2f(x1b.y), r1a);
    r2a = fmaf(w1b, bf2f(x1b.z), r2a); r3a = fmaf(w1b, bf2f(x1b.w), r3a);
  }
  if (va) {
    const float* e0p = (row0 < split) ? (e0U + (size_t)row0 * 64)
                                      : (e0I + (size_t)(row0 - split) * 64);
    float4 ev = *(const float4*)(e0p + k * 4);
    ushort4 o;
    o.x = f2bf(p0 + ALPHA * ev.x);
    o.y = f2bf(p1 + ALPHA * ev.y);
    o.z = f2bf(p2 + ALPHA * ev.z);
    o.w = f2bf(p3 + ALPHA * ev.w);
    *(ushort4*)(dst + (size_t)row0 * 64 + k * 4) = o;
  }
  if (vb) {
    const float* e0p = (row1 < split) ? (e0U + (size_t)row1 * 64)
                                      : (e0I + (size_t)(row1 - split) * 64);
    float4 ev = *(const float4*)(e0p + k * 4);
    ushort4 o;
    o.x = f2bf(r0a + ALPHA * ev.x);
    o.y = f2bf(r1a + ALPHA * ev.y);
    o.z = f2bf(r2a + ALPHA * ev.z);
    o.w = f2bf(r3a + ALPHA * ev.w);
    *(ushort4*)(dst + (size_t)row1 * 64 + k * 4) = o;
  }
}

__global__ __launch_bounds__(256) void k_spmm(
    const unsigned short* __restrict__ src,
    const float* __restrict__ e0U, const float* __restrict__ e0I, int split,
    const int* __restrict__ perm, const int* __restrict__ rowptrS, const int* __restrict__ lenS,
    const int2* __restrict__ colval,
    unsigned short* __restrict__ dst, int n) {
  spmm_body((int)(blockIdx.x * 256 + threadIdx.x), src, e0U, e0I, split,
            perm, rowptrS, lenS, colval, dst, n);
}

// spmm layer-2 with fused accA: acc = E0_f32[sample] + 3*bf2f(ebA[sample])
__global__ __launch_bounds__(256) void k_spmm2_acc(
    const unsigned short* __restrict__ ebA,
    const float* __restrict__ e0U, const float* __restrict__ e0I, int split,
    const int* __restrict__ perm, const int* __restrict__ rowptrS, const int* __restrict__ lenS,
    const int2* __restrict__ colval,
    unsigned short* __restrict__ ebB, int n, int spmmBlocks,
    const int* __restrict__ users, const int* __restrict__ items, int B,
    const float* __restrict__ user_emb, const float* __restrict__ item_emb,
    float* __restrict__ accU, float* __restrict__ accI) {
  if ((int)blockIdx.x < spmmBlocks) {
    spmm_body((int)(blockIdx.x * 256 + threadIdx.x), ebA, e0U, e0I, split,
              perm, rowptrS, lenS, colval, ebB, n);
  } else {
    int t = ((int)blockIdx.x - spmmBlocks) * 256 + threadIdx.x;
    int total = B * 64;
    if (t < total) {
      int b = t >> 6, d = t & 63;
      size_t idx = (size_t)users[b] * 64 + d;
      accU[t] = user_emb[idx] + 3.f * bf2f(ebA[idx]);
    } else if (t < 2 * total) {
      int t2 = t - total;
      int b = t2 >> 6, d = t2 & 63;
      int r = items[b];
      accI[t2] = item_emb[(size_t)r * 64 + d] + 3.f * bf2f(ebA[(size_t)(split + r) * 64 + d]);
    }
  }
}

// ---------------- fused layer-3 mini-SpMM + 2*E2 term (8192 sampled rows) ----------------

__global__ __launch_bounds__(256) void k_mini3(
    const int* __restrict__ users, const int* __restrict__ items, int B, int split,
    const unsigned short* __restrict__ ebB,
    const float* __restrict__ e0U, const float* __restrict__ e0I,
    const int* __restrict__ rowptr, const int* __restrict__ cnt,
    const int2* __restrict__ colval,
    float* __restrict__ accU, float* __restrict__ accI) {
  int wave = (int)((blockIdx.x * blockDim.x + threadIdx.x) >> 6);
  int lane = threadIdx.x & 63;
  int sub = lane >> 4;
  int k   = lane & 15;
  int idx = wave * 4 + sub;
  bool valid = idx < 2 * B;
  int ic = valid ? idx : 0;
  int row;
  float* accp;
  if (ic < B) { row = users[ic];             accp = accU + (size_t)ic * 64; }
  else        { row = split + items[ic - B]; accp = accI + (size_t)(ic - B) * 64; }
  int start = rowptr[row];
  int len   = valid ? cnt[row] : 0;
  int maxlen = len;
  maxlen = max(maxlen, __shfl_xor(maxlen, 16));
  maxlen = max(maxlen, __shfl_xor(maxlen, 32));
  const int2* cv = colval + start;
  const unsigned short* srcK = ebB + (size_t)k * 4;
  int lenm1 = (len > 0) ? (len - 1) : 0;

  float a0 = 0.f, a1 = 0.f, a2 = 0.f, a3 = 0.f;
  for (int j = 0; j < maxlen; j += 4) {
#pragma unroll
    for (int u = 0; u < 4; u++) {
      int jj = j + u;
      int jc = (jj < len) ? jj : lenm1;
      int2 e = cv[jc];
      float v = (jj < len) ? __int_as_float(e.y) : 0.f;
      ushort4 x = *(const ushort4*)(srcK + (size_t)e.x * 64);
      a0 = fmaf(v, bf2f(x.x), a0);
      a1 = fmaf(v, bf2f(x.y), a1);
      a2 = fmaf(v, bf2f(x.z), a2);
      a3 = fmaf(v, bf2f(x.w), a3);
    }
  }
  if (valid) {
    const float* e0p = (row < split) ? (e0U + (size_t)row * 64)
                                     : (e0I + (size_t)(row - split) * 64);
    float4 ev = *(const float4*)(e0p + k * 4);
    ushort4 x2 = *(const ushort4*)(srcK + (size_t)row * 64);  // E2[row], fused 2x term
    float4 cur = *(const float4*)(accp + k * 4);
    cur.x += a0 + ALPHA * ev.x + 2.f * bf2f(x2.x);
    cur.y += a1 + ALPHA * ev.y + 2.f * bf2f(x2.y);
    cur.z += a2 + ALPHA * ev.z + 2.f * bf2f(x2.z);
    cur.w += a3 + ALPHA * ev.w + 2.f * bf2f(x2.w);
    *(float4*)(accp + k * 4) = cur;
  }
}

__global__ void k_dot(const float* __restrict__ accU, const float* __restrict__ accI, int B,
                      float* __restrict__ out) {
  int wave = (int)((blockIdx.x * blockDim.x + threadIdx.x) >> 6);
  int lane = threadIdx.x & 63;
  if (wave >= B) return;
  float p = accU[(size_t)wave * 64 + lane] * accI[(size_t)wave * 64 + lane];
  for (int d = 32; d > 0; d >>= 1) p += __shfl_xor(p, d);
  if (lane == 0) out[wave] = p * (1.f / 16.f);  // (1/4) layer mean x (1/4) weight norm
}

// ---------------- launch ----------------

extern "C" void kernel_launch(void* const* d_in, const int* in_sizes, int n_in,
                              void* d_out, int out_size, void* d_ws, size_t ws_size,
                              hipStream_t stream) {
  const int*   users     = (const int*)d_in[0];
  const int*   items     = (const int*)d_in[1];
  const int*   rows      = (const int*)d_in[2];
  const int*   cols      = (const int*)d_in[3];
  const float* vals      = (const float*)d_in[4];
  const float* user_emb  = (const float*)d_in[5];
  const float* item_emb  = (const float*)d_in[6];
  const float* user_emb0 = (const float*)d_in[7];
  const float* item_emb0 = (const float*)d_in[8];
  float* gamma = (float*)d_out;

  int B   = in_sizes[0];
  int nnz = in_sizes[2];
  int nU  = in_sizes[5] / 64;
  int nI  = in_sizes[6] / 64;
  int N   = nU + nI;
  int nb  = (N + RPB - 1) >> BSHIFT;   // 147 buckets

  char* base = (char*)d_ws;
  unsigned short* ebIn = (unsigned short*)base;          // N*64 bf16
  unsigned short* ebA  = ebIn + (size_t)N * 64;          // N*64 bf16 (layer-1 out)
  unsigned short* ebB  = ebA  + (size_t)N * 64;          // N*64 bf16 (layer-2 out)
  uint2* pPay = (uint2*)ebA;                             // overlay: dead before layer-1 spmm
  char* p = (char*)(ebB + (size_t)N * 64);
  int2* colval  = (int2*)p;           p += ((size_t)nnz + 8) * sizeof(int2);
  int*  rowptr  = (int*)p;            p += (size_t)N * sizeof(int);
  int*  cnt     = (int*)p;            p += (size_t)N * sizeof(int);
  int*  perm    = (int*)p;            p += (size_t)N * sizeof(int);
  int*  rowptrS = (int*)p;            p += (size_t)N * sizeof(int);
  int*  lenS    = (int*)p;            p += (size_t)N * sizeof(int);
  int*  bcnt    = (int*)p;            p += MAXB * sizeof(int);
  int*  degHist = (int*)p;            p += 256 * sizeof(int);
  int*  bptr    = (int*)p;            p += (MAXB + 1) * sizeof(int);
  int*  bcur    = (int*)p;            p += MAXB * sizeof(int);
  int*  degCur  = (int*)p;            p += 256 * sizeof(int);
  float* accU   = (float*)p;          p += (size_t)B * 64 * sizeof(float);
  float* accI   = (float*)p;          p += (size_t)B * 64 * sizeof(float);

  hipMemsetAsync(bcnt, 0, (MAXB + 256) * sizeof(int), stream);  // bcnt + degHist contiguous

  const int tpb = 256;
  int nTot = N * 64;

  k_count<<<512, tpb, 0, stream>>>(rows, nnz, bcnt);
  k_scan_buckets<<<1, 256, 0, stream>>>(bcnt, nb, bptr, bcur);

  // fused partition + convert: partition blocks first, convert backfills
  int PB = (nnz + PCHUNK - 1) / PCHUNK;          // 306
  int convB = (nTot / 4 + 1023) / 1024;          // 4688
  k_part_conv<<<PB + convB, 1024, 0, stream>>>(rows, cols, vals, nnz, bcur, pPay, PB,
                                               user_emb, item_emb, nU * 64, nTot, ebIn);

  k_build_csr<<<nb, 1024, 0, stream>>>(bptr, pPay, N, rowptr, cnt, colval, degHist);
  k_degscan<<<1, 256, 0, stream>>>(degHist, degCur, colval, nnz);
  k_permute<<<(N + 1023) / 1024, tpb, 0, stream>>>(rowptr, cnt, N, degCur, perm, rowptrS, lenS);

  // 32 rows per 256-thread block (4 waves x 4 quarters x 2 rows)
  int spmmBlocks = (N + 31) / 32;
  int accBlocks = (2 * B * 64 + tpb - 1) / tpb;

  // layer 1: src = ebIn, dst = ebA (pPay dead from here)
  k_spmm<<<spmmBlocks, tpb, 0, stream>>>(ebIn, user_emb0, item_emb0, nU,
                                         perm, rowptrS, lenS, colval, ebA, N);

  // layer 2 + fused accA (E0 + 3*E1 at sampled rows)
  k_spmm2_acc<<<spmmBlocks + accBlocks, tpb, 0, stream>>>(ebA, user_emb0, item_emb0, nU,
                                                          perm, rowptrS, lenS, colval, ebB, N,
                                                          spmmBlocks, users, items, B,
                                                          user_emb, item_emb, accU, accI);

  // layer 3 sampled rows + fused 2*E2 term
  int mBlocks = (2 * B + 15) / 16;
  k_mini3<<<mBlocks, tpb, 0, stream>>>(users, items, B, nU, ebB,
                                       user_emb0, item_emb0,
                                       rowptr, cnt, colval, accU, accI);

  k_dot<<<(B * 64 + tpb - 1) / tpb, tpb, 0, stream>>>(accU, accI, B, gamma);
}

// Round 6
// 564.553 us; speedup vs baseline: 1.2720x; 1.0904x over previous
//
#include <hip/hip_runtime.h>

#define ALPHA 0.5f
#define BSHIFT 11                // 2048 rows per bucket
#define RPB 2048
#define MAXB 256                 // >= nBuckets (147)
#define PCHUNK 16384             // edges per partition block (1024 threads)

// ---------------- bf16 helpers ----------------

__device__ __forceinline__ float bf2f(unsigned short u) {
  return __uint_as_float((unsigned)u << 16);
}
__device__ __forceinline__ unsigned short f2bf(float f) {
  unsigned u = __float_as_uint(f);
  u += 0x7fffu + ((u >> 16) & 1u);   // round-to-nearest-even
  return (unsigned short)(u >> 16);
}

// ---------------- bucket counts only (rows -> bcnt) ----------------

__global__ __launch_bounds__(256) void k_count(
    const int* __restrict__ rows, int nnz, int* __restrict__ bcnt) {
  __shared__ int lcnt[MAXB];
  int t = threadIdx.x;
  if (t < MAXB) lcnt[t] = 0;
  __syncthreads();
  int stride = 512 * 256;
  for (int e = blockIdx.x * 256 + t; e < nnz; e += stride)
    atomicAdd(&lcnt[rows[e] >> BSHIFT], 1);
  __syncthreads();
  if (t < MAXB) {
    int c = lcnt[t];
    if (c) atomicAdd(&bcnt[t], c);
  }
}

// ---------------- scan bucket counts -> bptr, bcur ----------------

__global__ void k_scan_buckets(const int* __restrict__ bcnt, int nb,
                               int* __restrict__ bptr, int* __restrict__ bcur) {
  __shared__ int s[256];
  int t = threadIdx.x;
  int v = (t < nb) ? bcnt[t] : 0;
  s[t] = v; __syncthreads();
  for (int d = 1; d < 256; d <<= 1) {
    int x = (t >= d) ? s[t - d] : 0;
    __syncthreads();
    s[t] += x;
    __syncthreads();
  }
  if (t < nb) {
    int excl = s[t] - v;
    bptr[t] = excl;
    bcur[t] = excl;
  }
  if (t == 0) bptr[nb] = s[255];   // total
}

// ---------------- fused: partition (blocks < PB) + f32->bf16 convert ----------------

__global__ __launch_bounds__(1024) void k_part_conv(
    const int* __restrict__ rows, const int* __restrict__ cols, const float* __restrict__ vals,
    int nnz, int* __restrict__ bcur, uint2* __restrict__ pPay, int PB,
    const float* __restrict__ uE, const float* __restrict__ iE,
    int nU64, int nTot, unsigned short* __restrict__ out) {
  __shared__ int lcnt[MAXB];
  __shared__ int lbase[MAXB];
  int t = threadIdx.x;
  if ((int)blockIdx.x < PB) {
    if (t < MAXB) lcnt[t] = 0;
    __syncthreads();
    int base = blockIdx.x * PCHUNK;
    int end = nnz < base + PCHUNK ? nnz : base + PCHUNK;
    for (int e = base + t; e < end; e += 1024)
      atomicAdd(&lcnt[rows[e] >> BSHIFT], 1);
    __syncthreads();
    if (t < MAXB) {
      int c = lcnt[t];
      lbase[t] = c ? atomicAdd(&bcur[t], c) : 0;
      lcnt[t] = 0;
    }
    __syncthreads();
    for (int e = base + t; e < end; e += 1024) {
      int r = rows[e];
      int b = r >> BSHIFT;
      int p = lbase[b] + atomicAdd(&lcnt[b], 1);
      uint2 pay;
      pay.x = ((unsigned)(r & (RPB - 1)) << 20) | (unsigned)cols[e];
      pay.y = __float_as_uint(vals[e]);
      pPay[p] = pay;
    }
  } else {
    int i = (((int)blockIdx.x - PB) * 1024 + t) * 4;
    if (i >= nTot) return;
    const float* src = (i < nU64) ? (uE + i) : (iE + (i - nU64));
    float4 v = *(const float4*)src;
    ushort4 o;
    o.x = f2bf(v.x); o.y = f2bf(v.y); o.z = f2bf(v.z); o.w = f2bf(v.w);
    *(ushort4*)(out + i) = o;
  }
}

// ---------------- per-bucket CSR build + degree histogram (1024 thr, r4 win) ----------------

__global__ __launch_bounds__(1024) void k_build_csr(
    const int* __restrict__ bptr, const uint2* __restrict__ pPay, int N,
    int* __restrict__ rowptr, int* __restrict__ cnt, int2* __restrict__ colval,
    int* __restrict__ degHist) {
  __shared__ int lcnt[RPB];        // 8 KB: counts -> cursors
  __shared__ int scanbuf[1024];
  __shared__ int ldeg[256];
  int t = threadIdx.x;
  int b = blockIdx.x;
  int r0 = b << BSHIFT;
  int rCount = N - r0; if (rCount > RPB) rCount = RPB;
  int eBeg = bptr[b], eEnd = bptr[b + 1];

  for (int r = t; r < RPB; r += 1024) lcnt[r] = 0;
  if (t < 256) ldeg[t] = 0;
  __syncthreads();
  for (int e = eBeg + t; e < eEnd; e += 1024)
    atomicAdd(&lcnt[pPay[e].x >> 20], 1);
  __syncthreads();
  for (int r = t; r < rCount; r += 1024) {
    int c = lcnt[r];
    cnt[r0 + r] = c;
    atomicAdd(&ldeg[c < 255 ? c : 255], 1);
  }
  int v2[2]; int s = 0;
#pragma unroll
  for (int k = 0; k < 2; k++) {
    int x = lcnt[2 * t + k];
    v2[k] = s; s += x;
  }
  scanbuf[t] = s; __syncthreads();
  for (int d = 1; d < 1024; d <<= 1) {
    int x = (t >= d) ? scanbuf[t - d] : 0;
    __syncthreads();
    scanbuf[t] += x;
    __syncthreads();
  }
  int blockExcl = scanbuf[t] - s;
#pragma unroll
  for (int k = 0; k < 2; k++) lcnt[2 * t + k] = blockExcl + v2[k];
  __syncthreads();
  if (t < 256 && ldeg[t]) atomicAdd(&degHist[t], ldeg[t]);
  for (int r = t; r < rCount; r += 1024) rowptr[r0 + r] = eBeg + lcnt[r];
  __syncthreads();
  for (int e = eBeg + t; e < eEnd; e += 1024) {
    uint2 pay = pPay[e];
    int r = (int)(pay.x >> 20);
    int p = eBeg + atomicAdd(&lcnt[r], 1);
    int2 cv; cv.x = (int)(pay.x & 0xFFFFFu); cv.y = (int)pay.y;
    colval[p] = cv;
  }
}

// ---------------- degree-bin scan (1 block) + colval pad init ----------------

__global__ void k_degscan(const int* __restrict__ degHist, int* __restrict__ degCur,
                          int2* __restrict__ colval, int nnz) {
  __shared__ int s[256];
  int t = threadIdx.x;
  int v = degHist[t];
  s[t] = v; __syncthreads();
  for (int d = 1; d < 256; d <<= 1) {
    int x = (t >= d) ? s[t - d] : 0;
    __syncthreads();
    s[t] += x;
    __syncthreads();
  }
  degCur[t] = s[t] - v;   // exclusive
  if (t < 8) { int2 z; z.x = 0; z.y = 0; colval[nnz + t] = z; }
}

// ---------------- permute rows into degree-sorted order ----------------

__global__ __launch_bounds__(256) void k_permute(
    const int* __restrict__ rowptr, const int* __restrict__ cnt, int N,
    int* __restrict__ degCur,
    int* __restrict__ perm, int* __restrict__ rowptrS, int* __restrict__ lenS) {
  __shared__ int lcnt[256];
  __shared__ int lbase[256];
  int t = threadIdx.x;
  lcnt[t] = 0;
  __syncthreads();
  int base = blockIdx.x * 1024;
  int end = N < base + 1024 ? N : base + 1024;
  for (int r = base + t; r < end; r += 256) {
    int c = cnt[r];
    atomicAdd(&lcnt[c < 255 ? c : 255], 1);
  }
  __syncthreads();
  {
    int c = lcnt[t];
    lbase[t] = c ? atomicAdd(&degCur[t], c) : 0;
    lcnt[t] = 0;
  }
  __syncthreads();
  for (int r = base + t; r < end; r += 256) {
    int c = cnt[r];
    int bin = c < 255 ? c : 255;
    int pos = lbase[bin] + atomicAdd(&lcnt[bin], 1);
    perm[pos] = r;
    rowptrS[pos] = rowptr[r];
    lenS[pos] = c;
  }
}

// ---------------- SpMM core: quarter-wave owns 2 degree-adjacent rows ----------------
// (round-0 proven body; pipeline/unroll variants measured slower in r1/r2)

__device__ __forceinline__ void spmm_body(
    int gtid,
    const unsigned short* __restrict__ src,
    const float* __restrict__ e0U, const float* __restrict__ e0I, int split,
    const int* __restrict__ perm, const int* __restrict__ rowptrS, const int* __restrict__ lenS,
    const int2* __restrict__ colval,
    unsigned short* __restrict__ dst, int n) {
  int wave = gtid >> 6;
  int lane = gtid & 63;
  int sub = lane >> 4;
  int k   = lane & 15;
  int q = wave * 4 + sub;
  int s0 = 2 * q, s1 = 2 * q + 1;
  bool va = s0 < n, vb = s1 < n;
  int i0 = va ? s0 : 0, i1 = vb ? s1 : 0;
  int row0 = perm[i0], row1 = perm[i1];
  int st0 = rowptrS[i0], st1 = rowptrS[i1];
  int len0 = va ? lenS[i0] : 0, len1 = vb ? lenS[i1] : 0;
  const int2* cv0 = colval + st0;
  const int2* cv1 = colval + st1;
  const unsigned short* srcK = src + (size_t)k * 4;
  int l0m = len0 > 0 ? len0 - 1 : 0;
  int l1m = len1 > 0 ? len1 - 1 : 0;
  int mx = max(len0, len1);

  float p0 = 0.f, p1 = 0.f, p2 = 0.f, p3 = 0.f;   // row0
  float r0a = 0.f, r1a = 0.f, r2a = 0.f, r3a = 0.f; // row1
  for (int j = 0; j < mx; j += 2) {
    int ja = j, jb = j + 1;
    int j0a = ja < l0m ? ja : l0m, j0b = jb < l0m ? jb : l0m;
    int j1a = ja < l1m ? ja : l1m, j1b = jb < l1m ? jb : l1m;
    int2 e0a = cv0[j0a];
    int2 e0b = cv0[j0b];
    int2 e1a = cv1[j1a];
    int2 e1b = cv1[j1b];
    ushort4 x0a = *(const ushort4*)(srcK + (size_t)e0a.x * 64);
    ushort4 x0b = *(const ushort4*)(srcK + (size_t)e0b.x * 64);
    ushort4 x1a = *(const ushort4*)(srcK + (size_t)e1a.x * 64);
    ushort4 x1b = *(const ushort4*)(srcK + (size_t)e1b.x * 64);
    float w0a = ja < len0 ? __int_as_float(e0a.y) : 0.f;
    float w0b = jb < len0 ? __int_as_float(e0b.y) : 0.f;
    float w1a = ja < len1 ? __int_as_float(e1a.y) : 0.f;
    float w1b = jb < len1 ? __int_as_float(e1b.y) : 0.f;
    p0 = fmaf(w0a, bf2f(x0a.x), p0); p1 = fmaf(w0a, bf2f(x0a.y), p1);
    p2 = fmaf(w0a, bf2f(x0a.z), p2); p3 = fmaf(w0a, bf2f(x0a.w), p3);
    p0 = fmaf(w0b, bf2f(x0b.x), p0); p1 = fmaf(w0b, bf2f(x0b.y), p1);
    p2 = fmaf(w0b, bf2f(x0b.z), p2); p3 = fmaf(w0b, bf2f(x0b.w), p3);
    r0a = fmaf(w1a, bf2f(x1a.x), r0a); r1a = fmaf(w1a, bf2f(x1a.y), r1a);
    r2a = fmaf(w1a, bf2f(x1a.z), r2a); r3a = fmaf(w1a, bf2f(x1a.w), r3a);
    r0a = fmaf(w1b, bf2f(x1b.x), r0a); r1a = fmaf(w1b, bf2f(x1b.y), r1a);
    r2a = fmaf(w1b, bf2f(x1b.z), r2a); r3a = fmaf(w1b, bf2f(x1b.w), r3a);
  }
  if (va) {
    const float* e0p = (row0 < split) ? (e0U + (size_t)row0 * 64)
                                      : (e0I + (size_t)(row0 - split) * 64);
    float4 ev = *(const float4*)(e0p + k * 4);
    ushort4 o;
    o.x = f2bf(p0 + ALPHA * ev.x);
    o.y = f2bf(p1 + ALPHA * ev.y);
    o.z = f2bf(p2 + ALPHA * ev.z);
    o.w = f2bf(p3 + ALPHA * ev.w);
    *(ushort4*)(dst + (size_t)row0 * 64 + k * 4) = o;
  }
  if (vb) {
    const float* e0p = (row1 < split) ? (e0U + (size_t)row1 * 64)
                                      : (e0I + (size_t)(row1 - split) * 64);
    float4 ev = *(const float4*)(e0p + k * 4);
    ushort4 o;
    o.x = f2bf(r0a + ALPHA * ev.x);
    o.y = f2bf(r1a + ALPHA * ev.y);
    o.z = f2bf(r2a + ALPHA * ev.z);
    o.w = f2bf(r3a + ALPHA * ev.w);
    *(ushort4*)(dst + (size_t)row1 * 64 + k * 4) = o;
  }
}

// ---------------- layer-1 SpMM + fused needed-row marking ----------------
// mark blocks FIRST (overlap under the big SpMM): flag cols of sampled rows'
// edges + the sampled rows themselves. ebB is only ever read at flagged rows.

__global__ __launch_bounds__(256) void k_spmm1_mark(
    const unsigned short* __restrict__ src,
    const float* __restrict__ e0U, const float* __restrict__ e0I, int split,
    const int* __restrict__ perm, const int* __restrict__ rowptrS, const int* __restrict__ lenS,
    const int2* __restrict__ colval,
    unsigned short* __restrict__ dst, int n, int MB,
    const int* __restrict__ users, const int* __restrict__ items, int B,
    const int* __restrict__ rowptr, const int* __restrict__ cnt,
    unsigned char* __restrict__ flag) {
  if ((int)blockIdx.x < MB) {
    int t = (int)blockIdx.x * 256 + threadIdx.x;
    int wave = t >> 6;
    int lane = t & 63;
    int sub = lane >> 4;
    int k = lane & 15;
    int idx = wave * 4 + sub;
    if (idx >= 2 * B) return;
    int row = (idx < B) ? users[idx] : split + items[idx - B];
    if (k == 0) flag[row] = 1;
    int start = rowptr[row], len = cnt[row];
    for (int j = k; j < len; j += 16) flag[colval[start + j].x] = 1;
  } else {
    spmm_body((int)((blockIdx.x - MB) * 256 + threadIdx.x), src, e0U, e0I, split,
              perm, rowptrS, lenS, colval, dst, n);
  }
}

// ---------------- compact degree-sorted perm list to flagged rows ----------------
// Per-block LDS scan + one atomicAdd base: order preserved within block, blocks
// complete near-in-order -> degree adjacency (quarter-wave pairing) survives.

__global__ __launch_bounds__(1024) void k_compact(
    const int* __restrict__ perm, const int* __restrict__ rowptrS, const int* __restrict__ lenS,
    const unsigned char* __restrict__ flag, int N, int* __restrict__ selTotal,
    int* __restrict__ selPerm, int* __restrict__ selRowptrS, int* __restrict__ selLenS) {
  __shared__ int sbuf[1024];
  __shared__ int sbase;
  int t = threadIdx.x;
  int i = (int)blockIdx.x * 1024 + t;
  int f = 0, r = 0, rp = 0, ln = 0;
  if (i < N) {
    r = perm[i];
    f = flag[r];
    if (f) { rp = rowptrS[i]; ln = lenS[i]; }
  }
  sbuf[t] = f; __syncthreads();
  for (int d = 1; d < 1024; d <<= 1) {
    int x = (t >= d) ? sbuf[t - d] : 0;
    __syncthreads();
    sbuf[t] += x;
    __syncthreads();
  }
  int incl = sbuf[t];
  if (t == 1023) sbase = atomicAdd(selTotal, incl);
  __syncthreads();
  if (f) {
    int pos = sbase + incl - 1;
    selPerm[pos] = r;
    selRowptrS[pos] = rp;
    selLenS[pos] = ln;
  }
}

// spmm layer-2 (flagged rows only) + fused accA: acc = E0_f32[sample] + 3*bf2f(ebA[sample])
__global__ __launch_bounds__(256) void k_spmm2_acc(
    const unsigned short* __restrict__ ebA,
    const float* __restrict__ e0U, const float* __restrict__ e0I, int split,
    const int* __restrict__ selPerm, const int* __restrict__ selRowptrS,
    const int* __restrict__ selLenS, const int* __restrict__ nSelPtr,
    const int2* __restrict__ colval,
    unsigned short* __restrict__ ebB, int spmmBlocks,
    const int* __restrict__ users, const int* __restrict__ items, int B,
    const float* __restrict__ user_emb, const float* __restrict__ item_emb,
    float* __restrict__ accU, float* __restrict__ accI) {
  if ((int)blockIdx.x < spmmBlocks) {
    int nSel = *nSelPtr;
    spmm_body((int)(blockIdx.x * 256 + threadIdx.x), ebA, e0U, e0I, split,
              selPerm, selRowptrS, selLenS, colval, ebB, nSel);
  } else {
    int t = ((int)blockIdx.x - spmmBlocks) * 256 + threadIdx.x;
    int total = B * 64;
    if (t < total) {
      int b = t >> 6, d = t & 63;
      size_t idx = (size_t)users[b] * 64 + d;
      accU[t] = user_emb[idx] + 3.f * bf2f(ebA[idx]);
    } else if (t < 2 * total) {
      int t2 = t - total;
      int b = t2 >> 6, d = t2 & 63;
      int r = items[b];
      accI[t2] = item_emb[(size_t)r * 64 + d] + 3.f * bf2f(ebA[(size_t)(split + r) * 64 + d]);
    }
  }
}

// ---------------- fused layer-3 mini-SpMM + 2*E2 term (8192 sampled rows) ----------------
// fma guarded by jj<len: pruned (never-written) ebB rows are never gathered.

__global__ __launch_bounds__(256) void k_mini3(
    const int* __restrict__ users, const int* __restrict__ items, int B, int split,
    const unsigned short* __restrict__ ebB,
    const float* __restrict__ e0U, const float* __restrict__ e0I,
    const int* __restrict__ rowptr, const int* __restrict__ cnt,
    const int2* __restrict__ colval,
    float* __restrict__ accU, float* __restrict__ accI) {
  int wave = (int)((blockIdx.x * blockDim.x + threadIdx.x) >> 6);
  int lane = threadIdx.x & 63;
  int sub = lane >> 4;
  int k   = lane & 15;
  int idx = wave * 4 + sub;
  bool valid = idx < 2 * B;
  int ic = valid ? idx : 0;
  int row;
  float* accp;
  if (ic < B) { row = users[ic];             accp = accU + (size_t)ic * 64; }
  else        { row = split + items[ic - B]; accp = accI + (size_t)(ic - B) * 64; }
  int start = rowptr[row];
  int len   = valid ? cnt[row] : 0;
  int maxlen = len;
  maxlen = max(maxlen, __shfl_xor(maxlen, 16));
  maxlen = max(maxlen, __shfl_xor(maxlen, 32));
  const int2* cv = colval + start;
  const unsigned short* srcK = ebB + (size_t)k * 4;

  float a0 = 0.f, a1 = 0.f, a2 = 0.f, a3 = 0.f;
  for (int j = 0; j < maxlen; j += 4) {
#pragma unroll
    for (int u = 0; u < 4; u++) {
      int jj = j + u;
      if (jj < len) {
        int2 e = cv[jj];
        float v = __int_as_float(e.y);
        ushort4 x = *(const ushort4*)(srcK + (size_t)e.x * 64);
        a0 = fmaf(v, bf2f(x.x), a0);
        a1 = fmaf(v, bf2f(x.y), a1);
        a2 = fmaf(v, bf2f(x.z), a2);
        a3 = fmaf(v, bf2f(x.w), a3);
      }
    }
  }
  if (valid) {
    const float* e0p = (row < split) ? (e0U + (size_t)row * 64)
                                     : (e0I + (size_t)(row - split) * 64);
    float4 ev = *(const float4*)(e0p + k * 4);
    ushort4 x2 = *(const ushort4*)(srcK + (size_t)row * 64);  // E2[row], fused 2x term
    float4 cur = *(const float4*)(accp + k * 4);
    cur.x += a0 + ALPHA * ev.x + 2.f * bf2f(x2.x);
    cur.y += a1 + ALPHA * ev.y + 2.f * bf2f(x2.y);
    cur.z += a2 + ALPHA * ev.z + 2.f * bf2f(x2.z);
    cur.w += a3 + ALPHA * ev.w + 2.f * bf2f(x2.w);
    *(float4*)(accp + k * 4) = cur;
  }
}

__global__ void k_dot(const float* __restrict__ accU, const float* __restrict__ accI, int B,
                      float* __restrict__ out) {
  int wave = (int)((blockIdx.x * blockDim.x + threadIdx.x) >> 6);
  int lane = threadIdx.x & 63;
  if (wave >= B) return;
  float p = accU[(size_t)wave * 64 + lane] * accI[(size_t)wave * 64 + lane];
  for (int d = 32; d > 0; d >>= 1) p += __shfl_xor(p, d);
  if (lane == 0) out[wave] = p * (1.f / 16.f);  // (1/4) layer mean x (1/4) weight norm
}

// ---------------- launch ----------------

extern "C" void kernel_launch(void* const* d_in, const int* in_sizes, int n_in,
                              void* d_out, int out_size, void* d_ws, size_t ws_size,
                              hipStream_t stream) {
  const int*   users     = (const int*)d_in[0];
  const int*   items     = (const int*)d_in[1];
  const int*   rows      = (const int*)d_in[2];
  const int*   cols      = (const int*)d_in[3];
  const float* vals      = (const float*)d_in[4];
  const float* user_emb  = (const float*)d_in[5];
  const float* item_emb  = (const float*)d_in[6];
  const float* user_emb0 = (const float*)d_in[7];
  const float* item_emb0 = (const float*)d_in[8];
  float* gamma = (float*)d_out;

  int B   = in_sizes[0];
  int nnz = in_sizes[2];
  int nU  = in_sizes[5] / 64;
  int nI  = in_sizes[6] / 64;
  int N   = nU + nI;
  int nb  = (N + RPB - 1) >> BSHIFT;   // 147 buckets
  int Nf  = (N + 15) & ~15;            // flag bytes, 16B aligned

  char* base = (char*)d_ws;
  unsigned short* ebIn = (unsigned short*)base;          // N*64 bf16
  unsigned short* ebA  = ebIn + (size_t)N * 64;          // N*64 bf16 (layer-1 out)
  unsigned short* ebB  = ebA  + (size_t)N * 64;          // N*64 bf16 (layer-2 out, flagged rows only)
  uint2* pPay = (uint2*)ebA;                             // overlay: dead before layer-1 spmm
  char* p = (char*)(ebB + (size_t)N * 64);
  int2* colval  = (int2*)p;           p += ((size_t)nnz + 8) * sizeof(int2);
  int*  rowptr  = (int*)p;            p += (size_t)N * sizeof(int);
  int*  cnt     = (int*)p;            p += (size_t)N * sizeof(int);
  int*  perm    = (int*)p;            p += (size_t)N * sizeof(int);
  int*  rowptrS = (int*)p;            p += (size_t)N * sizeof(int);
  int*  lenS    = (int*)p;            p += (size_t)N * sizeof(int);
  int*  selPerm    = (int*)p;         p += (size_t)N * sizeof(int);
  int*  selRowptrS = (int*)p;         p += (size_t)N * sizeof(int);
  int*  selLenS    = (int*)p;         p += (size_t)N * sizeof(int);
  // zeroed region (one memset): bcnt, degHist, selTotal(+pad), flag
  int*  bcnt    = (int*)p;            p += MAXB * sizeof(int);
  int*  degHist = (int*)p;            p += 256 * sizeof(int);
  int*  selTotal= (int*)p;            p += 4 * sizeof(int);
  unsigned char* flag = (unsigned char*)p; p += Nf;
  int*  bptr    = (int*)p;            p += (MAXB + 1) * sizeof(int);
  int*  bcur    = (int*)p;            p += MAXB * sizeof(int);
  int*  degCur  = (int*)p;            p += 256 * sizeof(int);
  float* accU   = (float*)p;          p += (size_t)B * 64 * sizeof(float);
  float* accI   = (float*)p;          p += (size_t)B * 64 * sizeof(float);

  hipMemsetAsync(bcnt, 0, (MAXB + 256 + 4) * sizeof(int) + Nf, stream);

  const int tpb = 256;
  int nTot = N * 64;

  k_count<<<512, tpb, 0, stream>>>(rows, nnz, bcnt);
  k_scan_buckets<<<1, 256, 0, stream>>>(bcnt, nb, bptr, bcur);

  // fused partition + convert: partition blocks first, convert backfills
  int PB = (nnz + PCHUNK - 1) / PCHUNK;          // 306
  int convB = (nTot / 4 + 1023) / 1024;          // 4688
  k_part_conv<<<PB + convB, 1024, 0, stream>>>(rows, cols, vals, nnz, bcur, pPay, PB,
                                               user_emb, item_emb, nU * 64, nTot, ebIn);

  k_build_csr<<<nb, 1024, 0, stream>>>(bptr, pPay, N, rowptr, cnt, colval, degHist);
  k_degscan<<<1, 256, 0, stream>>>(degHist, degCur, colval, nnz);
  k_permute<<<(N + 1023) / 1024, tpb, 0, stream>>>(rowptr, cnt, N, degCur, perm, rowptrS, lenS);

  // 32 rows per 256-thread block (4 waves x 4 quarters x 2 rows)
  int spmmBlocks = (N + 31) / 32;
  int accBlocks = (2 * B * 64 + tpb - 1) / tpb;
  int markBlocks = (2 * B + 15) / 16;            // 512

  // layer 1 (all rows) + fused marking of ebB-needed rows (pPay dead from here)
  k_spmm1_mark<<<markBlocks + spmmBlocks, tpb, 0, stream>>>(
      ebIn, user_emb0, item_emb0, nU, perm, rowptrS, lenS, colval, ebA, N,
      markBlocks, users, items, B, rowptr, cnt, flag);

  // compact degree-sorted list to flagged rows (~38% of N)
  k_compact<<<(N + 1023) / 1024, 1024, 0, stream>>>(perm, rowptrS, lenS, flag, N,
                                                    selTotal, selPerm, selRowptrS, selLenS);

  // layer 2 on flagged rows only + fused accA (E0 + 3*E1 at sampled rows)
  k_spmm2_acc<<<spmmBlocks + accBlocks, tpb, 0, stream>>>(
      ebA, user_emb0, item_emb0, nU, selPerm, selRowptrS, selLenS, selTotal,
      colval, ebB, spmmBlocks, users, items, B, user_emb, item_emb, accU, accI);

  // layer 3 sampled rows + fused 2*E2 term
  int mBlocks = (2 * B + 15) / 16;
  k_mini3<<<mBlocks, tpb, 0, stream>>>(users, items, B, nU, ebB,
                                       user_emb0, item_emb0,
                                       rowptr, cnt, colval, accU, accI);

  k_dot<<<(B * 64 + tpb - 1) / tpb, tpb, 0, stream>>>(accU, accI, B, gamma);
}